// Round 16
// baseline (260.189 us; speedup 1.0000x reference)
//
#include <hip/hip_runtime.h>
#include <hip/hip_bf16.h>
#include <math.h>

typedef __attribute__((ext_vector_type(8))) short short8;
typedef __attribute__((ext_vector_type(4))) float f32x4;
typedef __attribute__((ext_vector_type(16))) float f32x16;
typedef __attribute__((ext_vector_type(4))) unsigned short ushort4v;
typedef __attribute__((ext_vector_type(4))) unsigned int u32x4;

#define D_MODEL 768
#define NH      12
#define DK      64
#define SEQ     1024
#define NB      8
#define MTOT    (NB*SEQ)                  // 8192
#define NELT    ((size_t)MTOT*D_MODEL)    // 6291456
#define WELT    ((size_t)D_MODEL*D_MODEL) // 589824
#define L2E     1.44269504088896f

__device__ __forceinline__ unsigned short f2bf(float f) {
    unsigned int u = __builtin_bit_cast(unsigned int, f);
    unsigned int r = (u + 0x7FFFu + ((u >> 16) & 1u)) >> 16;   // RNE
    return (unsigned short)r;
}
__device__ __forceinline__ unsigned short f2bf_rne(float f) {
    __hip_bfloat16 h = __float2bfloat16(f);       // compiler can pair into cvt_pk
    return __builtin_bit_cast(unsigned short, h);
}
__device__ __forceinline__ float bf2f(unsigned short h) {
    return __builtin_bit_cast(float, ((unsigned int)h) << 16);
}
__device__ __forceinline__ float fast_exp2(float x) {
#if __has_builtin(__builtin_amdgcn_exp2f)
    return __builtin_amdgcn_exp2f(x);        // bare v_exp_f32
#else
    return __expf(x * 0.69314718056f);
#endif
}
// pack two floats -> two bf16 (round-nearest) in one u32: {hi.bf16, lo.bf16}
__device__ __forceinline__ unsigned int pk_bf16_rn(float lo, float hi) {
    unsigned int ul = __builtin_bit_cast(unsigned int, lo) + 0x8000u;
    unsigned int uh = __builtin_bit_cast(unsigned int, hi) + 0x8000u;
    return __builtin_amdgcn_perm(uh, ul, 0x07060302u);  // {uh[3:2], ul[3:2]}
}
// v_permlane32_swap semantics: a.upper32lanes <-> b.lower32lanes
__device__ __forceinline__ void plswap(unsigned int &a, unsigned int &b, int g) {
#if __has_builtin(__builtin_amdgcn_permlane32_swap)
    typedef __attribute__((ext_vector_type(2))) unsigned int uint2v;
    uint2v r = __builtin_amdgcn_permlane32_swap(a, b, false, false);
    a = r[0]; b = r[1];
#else
    unsigned int sa = __shfl_xor(a, 32), sb = __shfl_xor(b, 32);
    unsigned int na = g ? sb : a;
    unsigned int nb = g ? b : sa;
    a = na; b = nb;
#endif
}
__device__ __forceinline__ void gload_lds16(const void* g, void* lds) {
    __builtin_amdgcn_global_load_lds(
        (const __attribute__((address_space(1))) unsigned int*)g,
        (__attribute__((address_space(3))) unsigned int*)lds, 16, 0, 0);
}

// ---------------------------------------------------------------------------
// fp32 -> bf16 convert: the 4 weight matrices only (small)
// ---------------------------------------------------------------------------
__global__ __launch_bounds__(256) void cvt_w(
    const float* __restrict__ a, const float* __restrict__ b,
    const float* __restrict__ c, const float* __restrict__ e,
    unsigned short* __restrict__ oa, unsigned short* __restrict__ ob,
    unsigned short* __restrict__ oc, unsigned short* __restrict__ oe)
{
    size_t i = (size_t)blockIdx.x * 256 + threadIdx.x;
    const size_t per = WELT / 8;
    const float* s; unsigned short* d; size_t l;
    if (i < per)        { s = a; d = oa; l = i; }
    else if (i < 2*per) { s = b; d = ob; l = i - per; }
    else if (i < 3*per) { s = c; d = oc; l = i - 2*per; }
    else                { s = e; d = oe; l = i - 3*per; }
    const float4* sp = (const float4*)(s + l*8);
    float4 v0 = sp[0], v1 = sp[1];
    short8 o;
    o[0]=(short)f2bf(v0.x); o[1]=(short)f2bf(v0.y); o[2]=(short)f2bf(v0.z); o[3]=(short)f2bf(v0.w);
    o[4]=(short)f2bf(v1.x); o[5]=(short)f2bf(v1.y); o[6]=(short)f2bf(v1.z); o[7]=(short)f2bf(v1.w);
    *(short8*)(d + l*8) = o;
}

// ---------------------------------------------------------------------------
// Merged projection GEMM, fp32 A direct via global_load_lds, BKP=32
// (unchanged from round 15 — wall-best variant).
// ---------------------------------------------------------------------------
#define BM 128
#define BN 128
#define BKG 64   // used by gemm_out only
#define BKP 32   // proj K-step

__global__ __launch_bounds__(256, 4) void proj_gemm(
    const float* __restrict__ Aq, const float* __restrict__ Ak, const float* __restrict__ Av,
    const unsigned short* __restrict__ Wq, const unsigned short* __restrict__ Wk,
    const unsigned short* __restrict__ Wv,
    const float* __restrict__ bq, const float* __restrict__ bk, const float* __restrict__ bv,
    unsigned short* __restrict__ Qp, unsigned short* __restrict__ Kp,
    unsigned short* __restrict__ Vtp)
{
    __shared__ float Asf[BM*BKP];
    __shared__ unsigned short Bs[BN*BKP];
    const int tid = threadIdx.x;
    const int lane = tid & 63, wid = tid >> 6;
    const int wr = wid >> 1, wc = wid & 1;

    const int bid = blockIdx.x;
    const int xcd = bid & 7;
    const int j = bid >> 3;
    const int mzL = j / 6, n = j % 6;
    const int mz = xcd * 24 + mzL;
    const int z = mz >> 6;
    const int m0 = (mz & 63) * BM, n0 = n * BN;

    const float* A          = (z == 0) ? Aq : (z == 1) ? Ak : Av;
    const unsigned short* W = (z == 0) ? Wq : (z == 1) ? Wk : Wv;
    const float* bias       = (z == 0) ? bq : (z == 1) ? bk : bv;

    f32x4 acc[4][4];
    #pragma unroll
    for (int i = 0; i < 4; ++i)
        #pragma unroll
        for (int jj = 0; jj < 4; ++jj) acc[i][jj] = (f32x4)(0.f);

    for (int k0 = 0; k0 < D_MODEL; k0 += BKP) {
        __syncthreads();
        #pragma unroll
        for (int c = 0; c < 4; ++c) {
            int chunk = wid*4 + c;
            int gI = (chunk << 6) + lane;
            int row = gI >> 3, gran = gI & 7;
            const float* srcA = A + (size_t)(m0+row)*D_MODEL + k0 + ((gran ^ (row & 7)) << 2);
            gload_lds16(srcA, (char*)Asf + (chunk << 10));
        }
        #pragma unroll
        for (int c = 0; c < 2; ++c) {
            int chunk = wid*2 + c;
            int gI = (chunk << 6) + lane;
            int row = gI >> 2, oct = gI & 3;
            const unsigned short* srcB = W + (size_t)(n0+row)*D_MODEL + k0
                                           + ((oct ^ ((row >> 1) & 3)) << 3);
            gload_lds16(srcB, (char*)Bs + (chunk << 10));
        }
        __syncthreads();
        {
            short8 af[4], bf8[4];
            const int g = lane >> 4;
            #pragma unroll
            for (int mi = 0; mi < 4; ++mi) {
                int row = wr*64 + mi*16 + (lane & 15);
                int g0 = 2*g;
                const float* r0 = Asf + row*8*4 + (((g0  ) ^ (row & 7)) << 2);
                const float* r1 = Asf + row*8*4 + (((g0+1) ^ (row & 7)) << 2);
                float4 a0 = *(const float4*)r0;
                float4 a1 = *(const float4*)r1;
                short8 v;
                v[0]=(short)f2bf_rne(a0.x); v[1]=(short)f2bf_rne(a0.y);
                v[2]=(short)f2bf_rne(a0.z); v[3]=(short)f2bf_rne(a0.w);
                v[4]=(short)f2bf_rne(a1.x); v[5]=(short)f2bf_rne(a1.y);
                v[6]=(short)f2bf_rne(a1.z); v[7]=(short)f2bf_rne(a1.w);
                af[mi] = v;
            }
            #pragma unroll
            for (int ni = 0; ni < 4; ++ni) {
                int row = wc*64 + ni*16 + (lane & 15);
                bf8[ni] = *(const short8*)&Bs[row*BKP + ((g ^ ((row >> 1) & 3)) << 3)];
            }
            #pragma unroll
            for (int mi = 0; mi < 4; ++mi)
                #pragma unroll
                for (int ni = 0; ni < 4; ++ni)
                    acc[mi][ni] = __builtin_amdgcn_mfma_f32_16x16x32_bf16(af[mi], bf8[ni], acc[mi][ni], 0, 0, 0);
        }
    }

    float bv4[4];
    #pragma unroll
    for (int ni = 0; ni < 4; ++ni) bv4[ni] = bias[n0 + wc*64 + ni*16 + (lane & 15)];

    if (z < 2) {
        unsigned short* C = (z == 0) ? Qp : Kp;
        const float scale = (z == 0) ? 0.125f : 1.0f;
        #pragma unroll
        for (int mi = 0; mi < 4; ++mi)
            #pragma unroll
            for (int ni = 0; ni < 4; ++ni) {
                int col = n0 + wc*64 + ni*16 + (lane & 15);
                int rbase = m0 + wr*64 + mi*16 + ((lane>>4)<<2);
                #pragma unroll
                for (int jj = 0; jj < 4; ++jj)
                    C[(size_t)(rbase+jj)*D_MODEL + col] = f2bf((acc[mi][ni][jj] + bv4[ni]) * scale);
            }
    } else {
        #pragma unroll
        for (int mi = 0; mi < 4; ++mi)
            #pragma unroll
            for (int ni = 0; ni < 4; ++ni) {
                int col = n0 + wc*64 + ni*16 + (lane & 15);
                int hh = col >> 6, dd = col & 63;
                int mrow = m0 + wr*64 + mi*16 + ((lane>>4)<<2);
                int bb = mrow >> 10, ss = mrow & (SEQ-1);
                ushort4v pk;
                #pragma unroll
                for (int jj = 0; jj < 4; ++jj) pk[jj] = f2bf(acc[mi][ni][jj] + bv4[ni]);
                *(ushort4v*)&Vtp[((size_t)(bb*NH + hh)*DK + dd)*SEQ + ss] = pk;
            }
    }
}

// ---------------------------------------------------------------------------
// Final GEMM: out_fp32 = Aop(bf16) @ wo^T + bo
// ---------------------------------------------------------------------------
__global__ __launch_bounds__(256) void gemm_out(
    const unsigned short* __restrict__ A, const unsigned short* __restrict__ W,
    const float* __restrict__ bias, float* __restrict__ C)
{
    __shared__ unsigned short As[BM*BKG];
    __shared__ unsigned short Bs[BN*BKG];
    const int tid = threadIdx.x;
    const int lane = tid & 63, wid = tid >> 6;
    const int wr = wid >> 1, wc = wid & 1;
    const int m0 = blockIdx.y * BM, n0 = blockIdx.x * BN;

    f32x4 acc[4][4];
    #pragma unroll
    for (int i = 0; i < 4; ++i)
        #pragma unroll
        for (int j = 0; j < 4; ++j) acc[i][j] = (f32x4)(0.f);

    for (int k0 = 0; k0 < D_MODEL; k0 += BKG) {
        __syncthreads();
        #pragma unroll
        for (int j = 0; j < 4; ++j) {
            int p = ((wid*4 + j) << 9) + lane*8;
            int row = p >> 6, off = p & 63;
            const unsigned short* srcA = A + (size_t)(m0+row)*D_MODEL + k0 + (off ^ ((row&7)<<3));
            gload_lds16(srcA, &As[(wid*4 + j) << 9]);
            const unsigned short* srcB = W + (size_t)(n0+row)*D_MODEL + k0 + (off ^ ((row&7)<<3));
            gload_lds16(srcB, &Bs[(wid*4 + j) << 9]);
        }
        __syncthreads();
        #pragma unroll
        for (int ks = 0; ks < 2; ++ks) {
            short8 af[4], bf8[4];
            #pragma unroll
            for (int mi = 0; mi < 4; ++mi) {
                int row = wr*64 + mi*16 + (lane & 15);
                af[mi] = *(const short8*)&As[row*BKG + ((ks*32 + (lane>>4)*8) ^ ((row&7)<<3))];
            }
            #pragma unroll
            for (int ni = 0; ni < 4; ++ni) {
                int row = wc*64 + ni*16 + (lane & 15);
                bf8[ni] = *(const short8*)&Bs[row*BKG + ((ks*32 + (lane>>4)*8) ^ ((row&7)<<3))];
            }
            #pragma unroll
            for (int mi = 0; mi < 4; ++mi)
                #pragma unroll
                for (int ni = 0; ni < 4; ++ni)
                    acc[mi][ni] = __builtin_amdgcn_mfma_f32_16x16x32_bf16(af[mi], bf8[ni], acc[mi][ni], 0, 0, 0);
        }
    }

    float bv4[4];
    #pragma unroll
    for (int ni = 0; ni < 4; ++ni) bv4[ni] = bias[n0 + wc*64 + ni*16 + (lane & 15)];

    #pragma unroll
    for (int mi = 0; mi < 4; ++mi)
        #pragma unroll
        for (int ni = 0; ni < 4; ++ni) {
            int col = n0 + wc*64 + ni*16 + (lane & 15);
            int rbase = m0 + wr*64 + mi*16 + ((lane>>4)<<2);
            #pragma unroll
            for (int j = 0; j < 4; ++j)
                C[(size_t)(rbase+j)*D_MODEL + col] = acc[mi][ni][j] + bv4[ni];
        }
}

// ---------------------------------------------------------------------------
// Flash attention, 32x32 MFMA, KVB=128 (8 chunks): halved per-chunk softmax
// overhead and staging-call count. Ks double-buffered (reg-staged);
// Vs SINGLE buffer (gload_lds) to keep 3 blocks/CU — vstage(ck+1) issued
// after the post-PV barrier, latency hidden under next QK phase.
// ---------------------------------------------------------------------------
#define KVB 128
#define NCH (SEQ/KVB)   // 8
#define THR 8.0f

__global__ __launch_bounds__(256, 3) void attn_flash(
    const unsigned short* __restrict__ Qp,
    const unsigned short* __restrict__ Kp,
    const unsigned short* __restrict__ Vt,
    const float* __restrict__ CW,
    unsigned short* __restrict__ Aop)
{
    __shared__ unsigned short Ks[2][130*64];  // 33.3 KB (keys ck*128-1..+128)
    __shared__ unsigned short Vs[64*128];     // 16.4 KB V^T chunk [64d][128k]

    const int tid = threadIdx.x;
    const int lane = tid & 63, wid = tid >> 6;
    const int ql = lane & 31, g = lane >> 5;

    const int bid = blockIdx.x;
    const int sw = (bid & 7) * 96 + (bid >> 3);
    const int q0 = (sw & 7) * 128;
    const int bh = sw >> 3;
    const int h = bh % NH, b = bh / NH;

    float wcv[9];
    #pragma unroll
    for (int i = 0; i < 9; ++i) wcv[i] = CW[h*9 + i];

    const unsigned short* KpB = Kp + (size_t)b*SEQ*D_MODEL + h*DK;
    const unsigned short* QpB = Qp + (size_t)b*SEQ*D_MODEL + h*DK;
    const char* VtB = (const char*)Vt + (size_t)bh*DK*SEQ*2;

    // ---- K chunk stage: 130 rows x 64 = 1040 granules, reg-staged ----
    short8 kreg[5];
    auto kload = [&](int ck) {
        #pragma unroll
        for (int u = 0; u < 5; ++u) {
            int idx = tid + u*256;
            short8 v = (short8)0;
            if (idx < 1040) {
                int r = idx >> 3, oct = idx & 7;
                int gk = ck*KVB - 1 + r;
                if (gk >= 0 && gk < SEQ)
                    v = *(const short8*)&KpB[(size_t)gk*D_MODEL + oct*8];
            }
            kreg[u] = v;
        }
    };
    auto kstore = [&](int buf) {
        #pragma unroll
        for (int u = 0; u < 5; ++u) {
            int idx = tid + u*256;
            if (idx < 1040) {
                int r = idx >> 3, oct = idx & 7;
                *(short8*)&Ks[buf][r*64 + ((oct ^ (r&7)) << 3)] = kreg[u];
            }
        }
    };
    // ---- V^T chunk stage via global_load_lds (single buffer) ----
    auto vstage = [&](int ck) {
        #pragma unroll
        for (int u = 0; u < 4; ++u) {
            int p = (tid + u*256) * 16;       // byte pos in 16 KB
            int row = p >> 8, off = p & 255;  // 256 B per d-row (128 keys)
            const char* src = VtB + ((size_t)row*SEQ + ck*KVB)*2 + (off ^ ((row&7)<<4));
            gload_lds16(src, (char*)Vs + p);
        }
    };

    kload(0);

    // ---- build Q~ B-frags from global (x log2e): q = ql, d-win = 16i+8g ----
    short8 qtf[3][4];
    {
        int gq = q0 + wid*32 + ql;
        #pragma unroll
        for (int i = 0; i < 4; ++i) {
            int dwin = i*16 + g*8;
            short8 qm = (short8)0, qc, qp8 = (short8)0;
            if (gq > 0)      qm  = *(const short8*)&QpB[(size_t)(gq-1)*D_MODEL + dwin];
            qc = *(const short8*)&QpB[(size_t)gq*D_MODEL + dwin];
            if (gq < SEQ-1)  qp8 = *(const short8*)&QpB[(size_t)(gq+1)*D_MODEL + dwin];
            short8 f0, f1, f2;
            #pragma unroll
            for (int j = 0; j < 8; ++j) {
                float fm = bf2f((unsigned short)qm[j]);
                float fc = bf2f((unsigned short)qc[j]);
                float fp = bf2f((unsigned short)qp8[j]);
                float t0 = (fc - (wcv[1]*fm + wcv[4]*fc + wcv[7]*fp)) * L2E;
                float t1 = -(wcv[0]*fm + wcv[3]*fc + wcv[6]*fp) * L2E;
                float t2 = -(wcv[2]*fm + wcv[5]*fc + wcv[8]*fp) * L2E;
                f0[j] = (short)f2bf(t0);
                f1[j] = (short)f2bf(t1);
                f2[j] = (short)f2bf(t2);
            }
            qtf[0][i] = f0; qtf[1][i] = f1; qtf[2][i] = f2;
        }
    }
    kstore(0);
    vstage(0);
    __syncthreads();

    float m = -1e30f, l = 0.f;
    f32x16 oac[2];
    oac[0] = (f32x16)(0.f); oac[1] = (f32x16)(0.f);

    int cur = 0;
    for (int ck = 0; ck < NCH; ++ck) {
        if (ck < NCH-1) kload(ck+1);   // K prefetch into regs (flies under QK)

        // ---- QK~^T: 4 k-tiles of 32; 3 slots x 4 d-slices each ----
        f32x16 st2[4];
        #pragma unroll
        for (int t = 0; t < 4; ++t) {
            f32x16 s = (f32x16)(0.f);
            #pragma unroll
            for (int sl = 0; sl < 3; ++sl) {
                const int shift = (sl == 0) ? 1 : (sl == 1) ? 0 : 2;
                int ar = t*32 + ql + shift;
                #pragma unroll
                for (int i = 0; i < 4; ++i) {
                    int oct = 2*i + g;
                    short8 a = *(const short8*)&Ks[cur][ar*64 + ((oct ^ (ar&7)) << 3)];
                    s = __builtin_amdgcn_mfma_f32_32x32x16_bf16(a, qtf[sl][i], s, 0, 0, 0);
                }
            }
            st2[t] = s;
        }

        // ---- online softmax, log2 domain, defer-rescale ----
        float tmax = -1e30f;
        #pragma unroll
        for (int t = 0; t < 4; ++t)
            #pragma unroll
            for (int j = 0; j < 16; ++j) tmax = fmaxf(tmax, st2[t][j]);
        tmax = fmaxf(tmax, __shfl_xor(tmax, 32));

        if (!__all(tmax - m <= THR)) {
            float mn = fmaxf(m, tmax);
            float r = fast_exp2(m - mn);
            l *= r;
            #pragma unroll
            for (int dt = 0; dt < 2; ++dt)
                #pragma unroll
                for (int j = 0; j < 16; ++j) oac[dt][j] *= r;
            m = mn;
        }
        float lsum = 0.f;
        #pragma unroll
        for (int t = 0; t < 4; ++t)
            #pragma unroll
            for (int j = 0; j < 16; ++j) {
                float e = fast_exp2(st2[t][j] - m);
                st2[t][j] = e;
                lsum += e;
            }
        lsum += __shfl_xor(lsum, 32);
        l += lsum;

        // ---- P B-frags in-register: pack + permlane32_swap ----
        short8 pf[8];
        #pragma unroll
        for (int t = 0; t < 4; ++t) {
            #pragma unroll
            for (int f = 0; f < 2; ++f) {
                const int base = f*8;
                unsigned int x0 = pk_bf16_rn(st2[t][base+0], st2[t][base+1]);
                unsigned int x1 = pk_bf16_rn(st2[t][base+2], st2[t][base+3]);
                unsigned int y0 = pk_bf16_rn(st2[t][base+4], st2[t][base+5]);
                unsigned int y1 = pk_bf16_rn(st2[t][base+6], st2[t][base+7]);
                plswap(x0, y0, g);
                plswap(x1, y1, g);
                u32x4 w = {x0, x1, y0, y1};
                pf[t*2 + f] = __builtin_bit_cast(short8, w);
            }
        }

        // ---- PV: 8 k-slices of 16; A = V^T frag from single Vs ----
        #pragma unroll
        for (int f = 0; f < 8; ++f) {
            #pragma unroll
            for (int dt = 0; dt < 2; ++dt) {
                int vr = dt*32 + ql;
                int oct = 2*f + g;                 // 16 k-granules per row
                short8 a = *(const short8*)&Vs[vr*128 + ((oct ^ (vr&7)) << 3)];
                oac[dt] = __builtin_amdgcn_mfma_f32_32x32x16_bf16(a, pf[f], oac[dt], 0, 0, 0);
            }
        }

        __syncthreads();                    // all PV reads of Vs done
        if (ck < NCH-1) { vstage(ck+1); kstore(cur^1); }
        __syncthreads();                    // Vs/Ks[cur^1] ready
        cur ^= 1;
    }

    float invl = 1.0f / l;
    int qg = q0 + wid*32 + ql;
    size_t obase = (size_t)(b*SEQ + qg)*D_MODEL + h*DK;
    #pragma unroll
    for (int dt = 0; dt < 2; ++dt) {
        #pragma unroll
        for (int u = 0; u < 4; ++u) {
            int d0 = dt*32 + 8*u + 4*g;
            ushort4v o;
            #pragma unroll
            for (int j = 0; j < 4; ++j) o[j] = f2bf(oac[dt][4*u + j] * invl);
            *(ushort4v*)&Aop[obase + d0] = o;
        }
    }
}

// ---------------------------------------------------------------------------
extern "C" void kernel_launch(void* const* d_in, const int* in_sizes, int n_in,
                              void* d_out, int out_size, void* d_ws, size_t ws_size,
                              hipStream_t stream)
{
    const float* q  = (const float*)d_in[0];
    const float* k  = (const float*)d_in[1];
    const float* v  = (const float*)d_in[2];
    const float* wq = (const float*)d_in[3];
    const float* bq = (const float*)d_in[4];
    const float* wk = (const float*)d_in[5];
    const float* bk = (const float*)d_in[6];
    const float* wv = (const float*)d_in[7];
    const float* bv = (const float*)d_in[8];
    const float* wo = (const float*)d_in[9];
    const float* bo = (const float*)d_in[10];
    const float* cw = (const float*)d_in[11];

    unsigned short* wqb = (unsigned short*)d_ws;
    unsigned short* wkb = wqb + WELT;
    unsigned short* wvb = wkb + WELT;
    unsigned short* wob = wvb + WELT;
    unsigned short* Qp  = wob + WELT;
    unsigned short* Kp  = Qp  + NELT;
    unsigned short* Vtp = Kp  + NELT;
    unsigned short* Aop = Vtp + NELT;

    cvt_w<<<(int)(4*WELT/8/256), 256, 0, stream>>>(wq, wk, wv, wo, wqb, wkb, wvb, wob);

    proj_gemm<<<dim3(1152), 256, 0, stream>>>(q, k, v, wqb, wkb, wvb,
                                              bq, bk, bv, Qp, Kp, Vtp);

    attn_flash<<<dim3(768), 256, 0, stream>>>(Qp, Kp, Vtp, cw, Aop);

    gemm_out<<<dim3(D_MODEL/BN, MTOT/BM), 256, 0, stream>>>(Aop, wob, bo, (float*)d_out);
}

// Round 17
// 152.609 us; speedup vs baseline: 1.7049x; 1.7049x over previous
//
#include <hip/hip_runtime.h>
#include <hip/hip_bf16.h>
#include <math.h>

typedef __attribute__((ext_vector_type(8))) short short8;
typedef __attribute__((ext_vector_type(4))) float f32x4;
typedef __attribute__((ext_vector_type(16))) float f32x16;
typedef __attribute__((ext_vector_type(4))) unsigned short ushort4v;
typedef __attribute__((ext_vector_type(4))) unsigned int u32x4;

#define D_MODEL 768
#define NH      12
#define DK      64
#define SEQ     1024
#define NB      8
#define MTOT    (NB*SEQ)                  // 8192
#define NELT    ((size_t)MTOT*D_MODEL)    // 6291456
#define WELT    ((size_t)D_MODEL*D_MODEL) // 589824
#define L2E     1.44269504088896f

__device__ __forceinline__ unsigned short f2bf(float f) {
    unsigned int u = __builtin_bit_cast(unsigned int, f);
    unsigned int r = (u + 0x7FFFu + ((u >> 16) & 1u)) >> 16;   // RNE
    return (unsigned short)r;
}
__device__ __forceinline__ unsigned short f2bf_rne(float f) {
    __hip_bfloat16 h = __float2bfloat16(f);       // compiler can pair into cvt_pk
    return __builtin_bit_cast(unsigned short, h);
}
__device__ __forceinline__ float bf2f(unsigned short h) {
    return __builtin_bit_cast(float, ((unsigned int)h) << 16);
}
__device__ __forceinline__ float fast_exp2(float x) {
#if __has_builtin(__builtin_amdgcn_exp2f)
    return __builtin_amdgcn_exp2f(x);        // bare v_exp_f32
#else
    return __expf(x * 0.69314718056f);
#endif
}
// pack two floats -> two bf16 (round-nearest) in one u32: {hi.bf16, lo.bf16}
__device__ __forceinline__ unsigned int pk_bf16_rn(float lo, float hi) {
    unsigned int ul = __builtin_bit_cast(unsigned int, lo) + 0x8000u;
    unsigned int uh = __builtin_bit_cast(unsigned int, hi) + 0x8000u;
    return __builtin_amdgcn_perm(uh, ul, 0x07060302u);  // {uh[3:2], ul[3:2]}
}
// v_permlane32_swap semantics: a.upper32lanes <-> b.lower32lanes
__device__ __forceinline__ void plswap(unsigned int &a, unsigned int &b, int g) {
#if __has_builtin(__builtin_amdgcn_permlane32_swap)
    typedef __attribute__((ext_vector_type(2))) unsigned int uint2v;
    uint2v r = __builtin_amdgcn_permlane32_swap(a, b, false, false);
    a = r[0]; b = r[1];
#else
    unsigned int sa = __shfl_xor(a, 32), sb = __shfl_xor(b, 32);
    unsigned int na = g ? sb : a;
    unsigned int nb = g ? b : sa;
    a = na; b = nb;
#endif
}
__device__ __forceinline__ void gload_lds16(const void* g, void* lds) {
    __builtin_amdgcn_global_load_lds(
        (const __attribute__((address_space(1))) unsigned int*)g,
        (__attribute__((address_space(3))) unsigned int*)lds, 16, 0, 0);
}

// ---------------------------------------------------------------------------
// fp32 -> bf16 convert: the 4 weight matrices only (small)
// ---------------------------------------------------------------------------
__global__ __launch_bounds__(256) void cvt_w(
    const float* __restrict__ a, const float* __restrict__ b,
    const float* __restrict__ c, const float* __restrict__ e,
    unsigned short* __restrict__ oa, unsigned short* __restrict__ ob,
    unsigned short* __restrict__ oc, unsigned short* __restrict__ oe)
{
    size_t i = (size_t)blockIdx.x * 256 + threadIdx.x;
    const size_t per = WELT / 8;
    const float* s; unsigned short* d; size_t l;
    if (i < per)        { s = a; d = oa; l = i; }
    else if (i < 2*per) { s = b; d = ob; l = i - per; }
    else if (i < 3*per) { s = c; d = oc; l = i - 2*per; }
    else                { s = e; d = oe; l = i - 3*per; }
    const float4* sp = (const float4*)(s + l*8);
    float4 v0 = sp[0], v1 = sp[1];
    short8 o;
    o[0]=(short)f2bf(v0.x); o[1]=(short)f2bf(v0.y); o[2]=(short)f2bf(v0.z); o[3]=(short)f2bf(v0.w);
    o[4]=(short)f2bf(v1.x); o[5]=(short)f2bf(v1.y); o[6]=(short)f2bf(v1.z); o[7]=(short)f2bf(v1.w);
    *(short8*)(d + l*8) = o;
}

// ---------------------------------------------------------------------------
// Merged projection GEMM, fp32 A direct via global_load_lds, BKP=32.
// XCD-grouped 1D grid: all 6 n-consumers of an A-tile share one L2.
// z = 0: Qp = (q@wq^T + bq)*0.125   z = 1: Kp   z = 2: Vt (transposed)
// ---------------------------------------------------------------------------
#define BM 128
#define BN 128
#define BKG 64   // used by gemm_out only
#define BKP 32   // proj K-step

__global__ __launch_bounds__(256, 4) void proj_gemm(
    const float* __restrict__ Aq, const float* __restrict__ Ak, const float* __restrict__ Av,
    const unsigned short* __restrict__ Wq, const unsigned short* __restrict__ Wk,
    const unsigned short* __restrict__ Wv,
    const float* __restrict__ bq, const float* __restrict__ bk, const float* __restrict__ bv,
    unsigned short* __restrict__ Qp, unsigned short* __restrict__ Kp,
    unsigned short* __restrict__ Vtp)
{
    __shared__ float Asf[BM*BKP];
    __shared__ unsigned short Bs[BN*BKP];
    const int tid = threadIdx.x;
    const int lane = tid & 63, wid = tid >> 6;
    const int wr = wid >> 1, wc = wid & 1;

    const int bid = blockIdx.x;
    const int xcd = bid & 7;
    const int j = bid >> 3;
    const int mzL = j / 6, n = j % 6;
    const int mz = xcd * 24 + mzL;
    const int z = mz >> 6;
    const int m0 = (mz & 63) * BM, n0 = n * BN;

    const float* A          = (z == 0) ? Aq : (z == 1) ? Ak : Av;
    const unsigned short* W = (z == 0) ? Wq : (z == 1) ? Wk : Wv;
    const float* bias       = (z == 0) ? bq : (z == 1) ? bk : bv;

    f32x4 acc[4][4];
    #pragma unroll
    for (int i = 0; i < 4; ++i)
        #pragma unroll
        for (int jj = 0; jj < 4; ++jj) acc[i][jj] = (f32x4)(0.f);

    for (int k0 = 0; k0 < D_MODEL; k0 += BKP) {
        __syncthreads();
        #pragma unroll
        for (int c = 0; c < 4; ++c) {
            int chunk = wid*4 + c;
            int gI = (chunk << 6) + lane;
            int row = gI >> 3, gran = gI & 7;
            const float* srcA = A + (size_t)(m0+row)*D_MODEL + k0 + ((gran ^ (row & 7)) << 2);
            gload_lds16(srcA, (char*)Asf + (chunk << 10));
        }
        #pragma unroll
        for (int c = 0; c < 2; ++c) {
            int chunk = wid*2 + c;
            int gI = (chunk << 6) + lane;
            int row = gI >> 2, oct = gI & 3;
            const unsigned short* srcB = W + (size_t)(n0+row)*D_MODEL + k0
                                           + ((oct ^ ((row >> 1) & 3)) << 3);
            gload_lds16(srcB, (char*)Bs + (chunk << 10));
        }
        __syncthreads();
        {
            short8 af[4], bf8[4];
            const int g = lane >> 4;
            #pragma unroll
            for (int mi = 0; mi < 4; ++mi) {
                int row = wr*64 + mi*16 + (lane & 15);
                int g0 = 2*g;
                const float* r0 = Asf + row*8*4 + (((g0  ) ^ (row & 7)) << 2);
                const float* r1 = Asf + row*8*4 + (((g0+1) ^ (row & 7)) << 2);
                float4 a0 = *(const float4*)r0;
                float4 a1 = *(const float4*)r1;
                short8 v;
                v[0]=(short)f2bf_rne(a0.x); v[1]=(short)f2bf_rne(a0.y);
                v[2]=(short)f2bf_rne(a0.z); v[3]=(short)f2bf_rne(a0.w);
                v[4]=(short)f2bf_rne(a1.x); v[5]=(short)f2bf_rne(a1.y);
                v[6]=(short)f2bf_rne(a1.z); v[7]=(short)f2bf_rne(a1.w);
                af[mi] = v;
            }
            #pragma unroll
            for (int ni = 0; ni < 4; ++ni) {
                int row = wc*64 + ni*16 + (lane & 15);
                bf8[ni] = *(const short8*)&Bs[row*BKP + ((g ^ ((row >> 1) & 3)) << 3)];
            }
            #pragma unroll
            for (int mi = 0; mi < 4; ++mi)
                #pragma unroll
                for (int ni = 0; ni < 4; ++ni)
                    acc[mi][ni] = __builtin_amdgcn_mfma_f32_16x16x32_bf16(af[mi], bf8[ni], acc[mi][ni], 0, 0, 0);
        }
    }

    float bv4[4];
    #pragma unroll
    for (int ni = 0; ni < 4; ++ni) bv4[ni] = bias[n0 + wc*64 + ni*16 + (lane & 15)];

    if (z < 2) {
        unsigned short* C = (z == 0) ? Qp : Kp;
        const float scale = (z == 0) ? 0.125f : 1.0f;
        #pragma unroll
        for (int mi = 0; mi < 4; ++mi)
            #pragma unroll
            for (int ni = 0; ni < 4; ++ni) {
                int col = n0 + wc*64 + ni*16 + (lane & 15);
                int rbase = m0 + wr*64 + mi*16 + ((lane>>4)<<2);
                #pragma unroll
                for (int jj = 0; jj < 4; ++jj)
                    C[(size_t)(rbase+jj)*D_MODEL + col] = f2bf((acc[mi][ni][jj] + bv4[ni]) * scale);
            }
    } else {
        #pragma unroll
        for (int mi = 0; mi < 4; ++mi)
            #pragma unroll
            for (int ni = 0; ni < 4; ++ni) {
                int col = n0 + wc*64 + ni*16 + (lane & 15);
                int hh = col >> 6, dd = col & 63;
                int mrow = m0 + wr*64 + mi*16 + ((lane>>4)<<2);
                int bb = mrow >> 10, ss = mrow & (SEQ-1);
                ushort4v pk;
                #pragma unroll
                for (int jj = 0; jj < 4; ++jj) pk[jj] = f2bf(acc[mi][ni][jj] + bv4[ni]);
                *(ushort4v*)&Vtp[((size_t)(bb*NH + hh)*DK + dd)*SEQ + ss] = pk;
            }
    }
}

// ---------------------------------------------------------------------------
// Final GEMM: out_fp32 = Aop(bf16) @ wo^T + bo
// ---------------------------------------------------------------------------
__global__ __launch_bounds__(256) void gemm_out(
    const unsigned short* __restrict__ A, const unsigned short* __restrict__ W,
    const float* __restrict__ bias, float* __restrict__ C)
{
    __shared__ unsigned short As[BM*BKG];
    __shared__ unsigned short Bs[BN*BKG];
    const int tid = threadIdx.x;
    const int lane = tid & 63, wid = tid >> 6;
    const int wr = wid >> 1, wc = wid & 1;
    const int m0 = blockIdx.y * BM, n0 = blockIdx.x * BN;

    f32x4 acc[4][4];
    #pragma unroll
    for (int i = 0; i < 4; ++i)
        #pragma unroll
        for (int j = 0; j < 4; ++j) acc[i][j] = (f32x4)(0.f);

    for (int k0 = 0; k0 < D_MODEL; k0 += BKG) {
        __syncthreads();
        #pragma unroll
        for (int j = 0; j < 4; ++j) {
            int p = ((wid*4 + j) << 9) + lane*8;
            int row = p >> 6, off = p & 63;
            const unsigned short* srcA = A + (size_t)(m0+row)*D_MODEL + k0 + (off ^ ((row&7)<<3));
            gload_lds16(srcA, &As[(wid*4 + j) << 9]);
            const unsigned short* srcB = W + (size_t)(n0+row)*D_MODEL + k0 + (off ^ ((row&7)<<3));
            gload_lds16(srcB, &Bs[(wid*4 + j) << 9]);
        }
        __syncthreads();
        #pragma unroll
        for (int ks = 0; ks < 2; ++ks) {
            short8 af[4], bf8[4];
            #pragma unroll
            for (int mi = 0; mi < 4; ++mi) {
                int row = wr*64 + mi*16 + (lane & 15);
                af[mi] = *(const short8*)&As[row*BKG + ((ks*32 + (lane>>4)*8) ^ ((row&7)<<3))];
            }
            #pragma unroll
            for (int ni = 0; ni < 4; ++ni) {
                int row = wc*64 + ni*16 + (lane & 15);
                bf8[ni] = *(const short8*)&Bs[row*BKG + ((ks*32 + (lane>>4)*8) ^ ((row&7)<<3))];
            }
            #pragma unroll
            for (int mi = 0; mi < 4; ++mi)
                #pragma unroll
                for (int ni = 0; ni < 4; ++ni)
                    acc[mi][ni] = __builtin_amdgcn_mfma_f32_16x16x32_bf16(af[mi], bf8[ni], acc[mi][ni], 0, 0, 0);
        }
    }

    float bv4[4];
    #pragma unroll
    for (int ni = 0; ni < 4; ++ni) bv4[ni] = bias[n0 + wc*64 + ni*16 + (lane & 15)];

    #pragma unroll
    for (int mi = 0; mi < 4; ++mi)
        #pragma unroll
        for (int ni = 0; ni < 4; ++ni) {
            int col = n0 + wc*64 + ni*16 + (lane & 15);
            int rbase = m0 + wr*64 + mi*16 + ((lane>>4)<<2);
            #pragma unroll
            for (int j = 0; j < 4; ++j)
                C[(size_t)(rbase+j)*D_MODEL + col] = acc[mi][ni][j] + bv4[ni];
        }
}

// ---------------------------------------------------------------------------
// Flash attention — round-13 verified body (71 us, 32x32 MFMA, KVB=64).
// ---------------------------------------------------------------------------
#define KVB 64
#define NCH (SEQ/KVB)   // 16
#define THR 8.0f

__global__ __launch_bounds__(256, 3) void attn_flash(
    const unsigned short* __restrict__ Qp,
    const unsigned short* __restrict__ Kp,
    const unsigned short* __restrict__ Vt,
    const float* __restrict__ CW,
    unsigned short* __restrict__ Aop)
{
    __shared__ unsigned short Ks[2][66*64];
    __shared__ unsigned short Vs[2][64*64];

    const int tid = threadIdx.x;
    const int lane = tid & 63, wid = tid >> 6;
    const int ql = lane & 31, g = lane >> 5;

    const int bid = blockIdx.x;
    const int sw = (bid & 7) * 96 + (bid >> 3);
    const int q0 = (sw & 7) * 128;
    const int bh = sw >> 3;
    const int h = bh % NH, b = bh / NH;

    float wcv[9];
    #pragma unroll
    for (int i = 0; i < 9; ++i) wcv[i] = CW[h*9 + i];

    const unsigned short* KpB = Kp + (size_t)b*SEQ*D_MODEL + h*DK;
    const unsigned short* QpB = Qp + (size_t)b*SEQ*D_MODEL + h*DK;
    const char* VtB = (const char*)Vt + (size_t)bh*DK*SEQ*2;

    short8 kreg[3];
    auto kload = [&](int ck) {
        #pragma unroll
        for (int u = 0; u < 3; ++u) {
            int idx = tid + u*256;
            short8 v = (short8)0;
            if (idx < 528) {
                int r = idx >> 3, oct = idx & 7;
                int gk = ck*KVB - 1 + r;
                if (gk >= 0 && gk < SEQ)
                    v = *(const short8*)&KpB[(size_t)gk*D_MODEL + oct*8];
            }
            kreg[u] = v;
        }
    };
    auto kstore = [&](int buf) {
        #pragma unroll
        for (int u = 0; u < 3; ++u) {
            int idx = tid + u*256;
            if (idx < 528) {
                int r = idx >> 3, oct = idx & 7;
                *(short8*)&Ks[buf][r*64 + ((oct ^ (r&7)) << 3)] = kreg[u];
            }
        }
    };
    auto vstage = [&](int ck, int buf) {
        #pragma unroll
        for (int u = 0; u < 2; ++u) {
            int p = (tid + u*256) * 16;
            int row = p >> 7, off = p & 127;
            const char* src = VtB + ((size_t)row*SEQ + ck*KVB)*2 + (off ^ ((row&7)<<4));
            gload_lds16(src, (char*)Vs[buf] + p);
        }
    };

    kload(0);

    short8 qtf[3][4];
    {
        int gq = q0 + wid*32 + ql;
        #pragma unroll
        for (int i = 0; i < 4; ++i) {
            int dwin = i*16 + g*8;
            short8 qm = (short8)0, qc, qp8 = (short8)0;
            if (gq > 0)      qm  = *(const short8*)&QpB[(size_t)(gq-1)*D_MODEL + dwin];
            qc = *(const short8*)&QpB[(size_t)gq*D_MODEL + dwin];
            if (gq < SEQ-1)  qp8 = *(const short8*)&QpB[(size_t)(gq+1)*D_MODEL + dwin];
            short8 f0, f1, f2;
            #pragma unroll
            for (int j = 0; j < 8; ++j) {
                float fm = bf2f((unsigned short)qm[j]);
                float fc = bf2f((unsigned short)qc[j]);
                float fp = bf2f((unsigned short)qp8[j]);
                float t0 = (fc - (wcv[1]*fm + wcv[4]*fc + wcv[7]*fp)) * L2E;
                float t1 = -(wcv[0]*fm + wcv[3]*fc + wcv[6]*fp) * L2E;
                float t2 = -(wcv[2]*fm + wcv[5]*fc + wcv[8]*fp) * L2E;
                f0[j] = (short)f2bf(t0);
                f1[j] = (short)f2bf(t1);
                f2[j] = (short)f2bf(t2);
            }
            qtf[0][i] = f0; qtf[1][i] = f1; qtf[2][i] = f2;
        }
    }
    kstore(0);
    vstage(0, 0);
    __syncthreads();

    float m = -1e30f, l = 0.f;
    f32x16 oac[2];
    oac[0] = (f32x16)(0.f); oac[1] = (f32x16)(0.f);

    int cur = 0;
    for (int ck = 0; ck < NCH; ++ck) {
        if (ck < NCH-1) { kload(ck+1); vstage(ck+1, cur^1); }

        f32x16 st2[2];
        #pragma unroll
        for (int t = 0; t < 2; ++t) {
            f32x16 s = (f32x16)(0.f);
            #pragma unroll
            for (int sl = 0; sl < 3; ++sl) {
                const int shift = (sl == 0) ? 1 : (sl == 1) ? 0 : 2;
                int ar = t*32 + ql + shift;
                #pragma unroll
                for (int i = 0; i < 4; ++i) {
                    int oct = 2*i + g;
                    short8 a = *(const short8*)&Ks[cur][ar*64 + ((oct ^ (ar&7)) << 3)];
                    s = __builtin_amdgcn_mfma_f32_32x32x16_bf16(a, qtf[sl][i], s, 0, 0, 0);
                }
            }
            st2[t] = s;
        }

        float tmax = -1e30f;
        #pragma unroll
        for (int t = 0; t < 2; ++t)
            #pragma unroll
            for (int j = 0; j < 16; ++j) tmax = fmaxf(tmax, st2[t][j]);
        tmax = fmaxf(tmax, __shfl_xor(tmax, 32));

        if (!__all(tmax - m <= THR)) {
            float mn = fmaxf(m, tmax);
            float r = fast_exp2(m - mn);
            l *= r;
            #pragma unroll
            for (int dt = 0; dt < 2; ++dt)
                #pragma unroll
                for (int j = 0; j < 16; ++j) oac[dt][j] *= r;
            m = mn;
        }
        float lsum = 0.f;
        #pragma unroll
        for (int t = 0; t < 2; ++t)
            #pragma unroll
            for (int j = 0; j < 16; ++j) {
                float e = fast_exp2(st2[t][j] - m);
                st2[t][j] = e;
                lsum += e;
            }
        lsum += __shfl_xor(lsum, 32);
        l += lsum;

        short8 pf[4];
        #pragma unroll
        for (int t = 0; t < 2; ++t) {
            #pragma unroll
            for (int f = 0; f < 2; ++f) {
                const int base = f*8;
                unsigned int x0 = pk_bf16_rn(st2[t][base+0], st2[t][base+1]);
                unsigned int x1 = pk_bf16_rn(st2[t][base+2], st2[t][base+3]);
                unsigned int y0 = pk_bf16_rn(st2[t][base+4], st2[t][base+5]);
                unsigned int y1 = pk_bf16_rn(st2[t][base+6], st2[t][base+7]);
                plswap(x0, y0, g);
                plswap(x1, y1, g);
                u32x4 w = {x0, x1, y0, y1};
                pf[t*2 + f] = __builtin_bit_cast(short8, w);
            }
        }

        #pragma unroll
        for (int f = 0; f < 4; ++f) {
            #pragma unroll
            for (int dt = 0; dt < 2; ++dt) {
                int vr = dt*32 + ql;
                int oct = 2*f + g;
                short8 a = *(const short8*)&Vs[cur][vr*64 + ((oct ^ (vr&7)) << 3)];
                oac[dt] = __builtin_amdgcn_mfma_f32_32x32x16_bf16(a, pf[f], oac[dt], 0, 0, 0);
            }
        }

        if (ck < NCH-1) kstore(cur^1);
        __syncthreads();
        cur ^= 1;
    }

    float invl = 1.0f / l;
    int qg = q0 + wid*32 + ql;
    size_t obase = (size_t)(b*SEQ + qg)*D_MODEL + h*DK;
    #pragma unroll
    for (int dt = 0; dt < 2; ++dt) {
        #pragma unroll
        for (int u = 0; u < 4; ++u) {
            int d0 = dt*32 + 8*u + 4*g;
            ushort4v o;
            #pragma unroll
            for (int j = 0; j < 4; ++j) o[j] = f2bf(oac[dt][4*u + j] * invl);
            *(ushort4v*)&Aop[obase + d0] = o;
        }
    }
}

// ---------------------------------------------------------------------------
extern "C" void kernel_launch(void* const* d_in, const int* in_sizes, int n_in,
                              void* d_out, int out_size, void* d_ws, size_t ws_size,
                              hipStream_t stream)
{
    const float* q  = (const float*)d_in[0];
    const float* k  = (const float*)d_in[1];
    const float* v  = (const float*)d_in[2];
    const float* wq = (const float*)d_in[3];
    const float* bq = (const float*)d_in[4];
    const float* wk = (const float*)d_in[5];
    const float* bk = (const float*)d_in[6];
    const float* wv = (const float*)d_in[7];
    const float* bv = (const float*)d_in[8];
    const float* wo = (const float*)d_in[9];
    const float* bo = (const float*)d_in[10];
    const float* cw = (const float*)d_in[11];

    unsigned short* wqb = (unsigned short*)d_ws;
    unsigned short* wkb = wqb + WELT;
    unsigned short* wvb = wkb + WELT;
    unsigned short* wob = wvb + WELT;
    unsigned short* Qp  = wob + WELT;
    unsigned short* Kp  = Qp  + NELT;
    unsigned short* Vtp = Kp  + NELT;
    unsigned short* Aop = Vtp + NELT;

    cvt_w<<<(int)(4*WELT/8/256), 256, 0, stream>>>(wq, wk, wv, wo, wqb, wkb, wvb, wob);

    proj_gemm<<<dim3(1152), 256, 0, stream>>>(q, k, v, wqb, wkb, wvb,
                                              bq, bk, bv, Qp, Kp, Vtp);

    attn_flash<<<dim3(768), 256, 0, stream>>>(Qp, Kp, Vtp, cw, Aop);

    gemm_out<<<dim3(D_MODEL/BN, MTOT/BM), 256, 0, stream>>>(Aop, wob, bo, (float*)d_out);
}

// Round 18
// 151.522 us; speedup vs baseline: 1.7172x; 1.0072x over previous
//
#include <hip/hip_runtime.h>
#include <hip/hip_bf16.h>
#include <math.h>

typedef __attribute__((ext_vector_type(8))) short short8;
typedef __attribute__((ext_vector_type(4))) float f32x4;
typedef __attribute__((ext_vector_type(16))) float f32x16;
typedef __attribute__((ext_vector_type(4))) unsigned short ushort4v;
typedef __attribute__((ext_vector_type(4))) unsigned int u32x4;

#define D_MODEL 768
#define NH      12
#define DK      64
#define SEQ     1024
#define NB      8
#define MTOT    (NB*SEQ)                  // 8192
#define NELT    ((size_t)MTOT*D_MODEL)    // 6291456
#define WELT    ((size_t)D_MODEL*D_MODEL) // 589824
#define L2E     1.44269504088896f

__device__ __forceinline__ unsigned short f2bf(float f) {
    unsigned int u = __builtin_bit_cast(unsigned int, f);
    unsigned int r = (u + 0x7FFFu + ((u >> 16) & 1u)) >> 16;   // RNE
    return (unsigned short)r;
}
__device__ __forceinline__ unsigned short f2bf_rne(float f) {
    __hip_bfloat16 h = __float2bfloat16(f);       // compiler can pair into cvt_pk
    return __builtin_bit_cast(unsigned short, h);
}
__device__ __forceinline__ float bf2f(unsigned short h) {
    return __builtin_bit_cast(float, ((unsigned int)h) << 16);
}
__device__ __forceinline__ float fast_exp2(float x) {
#if __has_builtin(__builtin_amdgcn_exp2f)
    return __builtin_amdgcn_exp2f(x);        // bare v_exp_f32
#else
    return __expf(x * 0.69314718056f);
#endif
}
// pack two floats -> two bf16 (round-nearest) in one u32: {hi.bf16, lo.bf16}
__device__ __forceinline__ unsigned int pk_bf16_rn(float lo, float hi) {
    unsigned int ul = __builtin_bit_cast(unsigned int, lo) + 0x8000u;
    unsigned int uh = __builtin_bit_cast(unsigned int, hi) + 0x8000u;
    return __builtin_amdgcn_perm(uh, ul, 0x07060302u);  // {uh[3:2], ul[3:2]}
}
// v_permlane32_swap semantics: a.upper32lanes <-> b.lower32lanes
__device__ __forceinline__ void plswap(unsigned int &a, unsigned int &b, int g) {
#if __has_builtin(__builtin_amdgcn_permlane32_swap)
    typedef __attribute__((ext_vector_type(2))) unsigned int uint2v;
    uint2v r = __builtin_amdgcn_permlane32_swap(a, b, false, false);
    a = r[0]; b = r[1];
#else
    unsigned int sa = __shfl_xor(a, 32), sb = __shfl_xor(b, 32);
    unsigned int na = g ? sb : a;
    unsigned int nb = g ? b : sa;
    a = na; b = nb;
#endif
}
__device__ __forceinline__ void gload_lds16(const void* g, void* lds) {
    __builtin_amdgcn_global_load_lds(
        (const __attribute__((address_space(1))) unsigned int*)g,
        (__attribute__((address_space(3))) unsigned int*)lds, 16, 0, 0);
}

// ---------------------------------------------------------------------------
// fp32 -> bf16 convert: the 4 weight matrices only (small)
// ---------------------------------------------------------------------------
__global__ __launch_bounds__(256) void cvt_w(
    const float* __restrict__ a, const float* __restrict__ b,
    const float* __restrict__ c, const float* __restrict__ e,
    unsigned short* __restrict__ oa, unsigned short* __restrict__ ob,
    unsigned short* __restrict__ oc, unsigned short* __restrict__ oe)
{
    size_t i = (size_t)blockIdx.x * 256 + threadIdx.x;
    const size_t per = WELT / 8;
    const float* s; unsigned short* d; size_t l;
    if (i < per)        { s = a; d = oa; l = i; }
    else if (i < 2*per) { s = b; d = ob; l = i - per; }
    else if (i < 3*per) { s = c; d = oc; l = i - 2*per; }
    else                { s = e; d = oe; l = i - 3*per; }
    const float4* sp = (const float4*)(s + l*8);
    float4 v0 = sp[0], v1 = sp[1];
    short8 o;
    o[0]=(short)f2bf(v0.x); o[1]=(short)f2bf(v0.y); o[2]=(short)f2bf(v0.z); o[3]=(short)f2bf(v0.w);
    o[4]=(short)f2bf(v1.x); o[5]=(short)f2bf(v1.y); o[6]=(short)f2bf(v1.z); o[7]=(short)f2bf(v1.w);
    *(short8*)(d + l*8) = o;
}

// ---------------------------------------------------------------------------
// Merged projection GEMM, fp32 A direct via global_load_lds, BKP=32,
// DOUBLE-BUFFERED stage-ahead: issue tile t+1's gload_lds before computing
// tile t; single barrier per K-step (its implicit vmcnt(0) drain is the
// pipeline wait). LDS 48 KB -> 3 blocks/CU.
// z = 0: Qp = (q@wq^T + bq)*0.125   z = 1: Kp   z = 2: Vt (transposed)
// ---------------------------------------------------------------------------
#define BM 128
#define BN 128
#define BKG 64   // used by gemm_out only
#define BKP 32   // proj K-step
#define NKP (D_MODEL/BKP)   // 24

__global__ __launch_bounds__(256, 3) void proj_gemm(
    const float* __restrict__ Aq, const float* __restrict__ Ak, const float* __restrict__ Av,
    const unsigned short* __restrict__ Wq, const unsigned short* __restrict__ Wk,
    const unsigned short* __restrict__ Wv,
    const float* __restrict__ bq, const float* __restrict__ bk, const float* __restrict__ bv,
    unsigned short* __restrict__ Qp, unsigned short* __restrict__ Kp,
    unsigned short* __restrict__ Vtp)
{
    __shared__ float Asf[2][BM*BKP];           // 2 x 16 KB
    __shared__ unsigned short Bs[2][BN*BKP];   // 2 x 8 KB
    const int tid = threadIdx.x;
    const int lane = tid & 63, wid = tid >> 6;
    const int wr = wid >> 1, wc = wid & 1;

    const int bid = blockIdx.x;
    const int xcd = bid & 7;
    const int j = bid >> 3;
    const int mzL = j / 6, n = j % 6;
    const int mz = xcd * 24 + mzL;
    const int z = mz >> 6;
    const int m0 = (mz & 63) * BM, n0 = n * BN;

    const float* A          = (z == 0) ? Aq : (z == 1) ? Ak : Av;
    const unsigned short* W = (z == 0) ? Wq : (z == 1) ? Wk : Wv;
    const float* bias       = (z == 0) ? bq : (z == 1) ? bk : bv;

    f32x4 acc[4][4];
    #pragma unroll
    for (int i = 0; i < 4; ++i)
        #pragma unroll
        for (int jj = 0; jj < 4; ++jj) acc[i][jj] = (f32x4)(0.f);

    auto stage = [&](int buf, int k0) {
        #pragma unroll
        for (int c = 0; c < 4; ++c) {
            int chunk = wid*4 + c;
            int gI = (chunk << 6) + lane;
            int row = gI >> 3, gran = gI & 7;
            const float* srcA = A + (size_t)(m0+row)*D_MODEL + k0 + ((gran ^ (row & 7)) << 2);
            gload_lds16(srcA, (char*)Asf[buf] + (chunk << 10));
        }
        #pragma unroll
        for (int c = 0; c < 2; ++c) {
            int chunk = wid*2 + c;
            int gI = (chunk << 6) + lane;
            int row = gI >> 2, oct = gI & 3;
            const unsigned short* srcB = W + (size_t)(n0+row)*D_MODEL + k0
                                           + ((oct ^ ((row >> 1) & 3)) << 3);
            gload_lds16(srcB, (char*)Bs[buf] + (chunk << 10));
        }
    };

    stage(0, 0);
    __syncthreads();                 // tile 0 resident
    int buf = 0;
    for (int t = 0; t < NKP; ++t) {
        if (t + 1 < NKP) stage(buf ^ 1, (t + 1) * BKP);   // issue-ahead
        {
            short8 af[4], bf8[4];
            const int g = lane >> 4;
            #pragma unroll
            for (int mi = 0; mi < 4; ++mi) {
                int row = wr*64 + mi*16 + (lane & 15);
                int g0 = 2*g;
                const float* r0 = Asf[buf] + row*8*4 + (((g0  ) ^ (row & 7)) << 2);
                const float* r1 = Asf[buf] + row*8*4 + (((g0+1) ^ (row & 7)) << 2);
                float4 a0 = *(const float4*)r0;
                float4 a1 = *(const float4*)r1;
                short8 v;
                v[0]=(short)f2bf_rne(a0.x); v[1]=(short)f2bf_rne(a0.y);
                v[2]=(short)f2bf_rne(a0.z); v[3]=(short)f2bf_rne(a0.w);
                v[4]=(short)f2bf_rne(a1.x); v[5]=(short)f2bf_rne(a1.y);
                v[6]=(short)f2bf_rne(a1.z); v[7]=(short)f2bf_rne(a1.w);
                af[mi] = v;
            }
            #pragma unroll
            for (int ni = 0; ni < 4; ++ni) {
                int row = wc*64 + ni*16 + (lane & 15);
                bf8[ni] = *(const short8*)&Bs[buf][row*BKP + ((g ^ ((row >> 1) & 3)) << 3)];
            }
            #pragma unroll
            for (int mi = 0; mi < 4; ++mi)
                #pragma unroll
                for (int ni = 0; ni < 4; ++ni)
                    acc[mi][ni] = __builtin_amdgcn_mfma_f32_16x16x32_bf16(af[mi], bf8[ni], acc[mi][ni], 0, 0, 0);
        }
        __syncthreads();   // drains vmcnt -> next buf ready; WAR-protects buf
        buf ^= 1;
    }

    float bv4[4];
    #pragma unroll
    for (int ni = 0; ni < 4; ++ni) bv4[ni] = bias[n0 + wc*64 + ni*16 + (lane & 15)];

    if (z < 2) {
        unsigned short* C = (z == 0) ? Qp : Kp;
        const float scale = (z == 0) ? 0.125f : 1.0f;
        #pragma unroll
        for (int mi = 0; mi < 4; ++mi)
            #pragma unroll
            for (int ni = 0; ni < 4; ++ni) {
                int col = n0 + wc*64 + ni*16 + (lane & 15);
                int rbase = m0 + wr*64 + mi*16 + ((lane>>4)<<2);
                #pragma unroll
                for (int jj = 0; jj < 4; ++jj)
                    C[(size_t)(rbase+jj)*D_MODEL + col] = f2bf((acc[mi][ni][jj] + bv4[ni]) * scale);
            }
    } else {
        #pragma unroll
        for (int mi = 0; mi < 4; ++mi)
            #pragma unroll
            for (int ni = 0; ni < 4; ++ni) {
                int col = n0 + wc*64 + ni*16 + (lane & 15);
                int hh = col >> 6, dd = col & 63;
                int mrow = m0 + wr*64 + mi*16 + ((lane>>4)<<2);
                int bb = mrow >> 10, ss = mrow & (SEQ-1);
                ushort4v pk;
                #pragma unroll
                for (int jj = 0; jj < 4; ++jj) pk[jj] = f2bf(acc[mi][ni][jj] + bv4[ni]);
                *(ushort4v*)&Vtp[((size_t)(bb*NH + hh)*DK + dd)*SEQ + ss] = pk;
            }
    }
}

// ---------------------------------------------------------------------------
// Final GEMM: out_fp32 = Aop(bf16) @ wo^T + bo
// ---------------------------------------------------------------------------
__global__ __launch_bounds__(256) void gemm_out(
    const unsigned short* __restrict__ A, const unsigned short* __restrict__ W,
    const float* __restrict__ bias, float* __restrict__ C)
{
    __shared__ unsigned short As[BM*BKG];
    __shared__ unsigned short Bs[BN*BKG];
    const int tid = threadIdx.x;
    const int lane = tid & 63, wid = tid >> 6;
    const int wr = wid >> 1, wc = wid & 1;
    const int m0 = blockIdx.y * BM, n0 = blockIdx.x * BN;

    f32x4 acc[4][4];
    #pragma unroll
    for (int i = 0; i < 4; ++i)
        #pragma unroll
        for (int j = 0; j < 4; ++j) acc[i][j] = (f32x4)(0.f);

    for (int k0 = 0; k0 < D_MODEL; k0 += BKG) {
        __syncthreads();
        #pragma unroll
        for (int j = 0; j < 4; ++j) {
            int p = ((wid*4 + j) << 9) + lane*8;
            int row = p >> 6, off = p & 63;
            const unsigned short* srcA = A + (size_t)(m0+row)*D_MODEL + k0 + (off ^ ((row&7)<<3));
            gload_lds16(srcA, &As[(wid*4 + j) << 9]);
            const unsigned short* srcB = W + (size_t)(n0+row)*D_MODEL + k0 + (off ^ ((row&7)<<3));
            gload_lds16(srcB, &Bs[(wid*4 + j) << 9]);
        }
        __syncthreads();
        #pragma unroll
        for (int ks = 0; ks < 2; ++ks) {
            short8 af[4], bf8[4];
            #pragma unroll
            for (int mi = 0; mi < 4; ++mi) {
                int row = wr*64 + mi*16 + (lane & 15);
                af[mi] = *(const short8*)&As[row*BKG + ((ks*32 + (lane>>4)*8) ^ ((row&7)<<3))];
            }
            #pragma unroll
            for (int ni = 0; ni < 4; ++ni) {
                int row = wc*64 + ni*16 + (lane & 15);
                bf8[ni] = *(const short8*)&Bs[row*BKG + ((ks*32 + (lane>>4)*8) ^ ((row&7)<<3))];
            }
            #pragma unroll
            for (int mi = 0; mi < 4; ++mi)
                #pragma unroll
                for (int ni = 0; ni < 4; ++ni)
                    acc[mi][ni] = __builtin_amdgcn_mfma_f32_16x16x32_bf16(af[mi], bf8[ni], acc[mi][ni], 0, 0, 0);
        }
    }

    float bv4[4];
    #pragma unroll
    for (int ni = 0; ni < 4; ++ni) bv4[ni] = bias[n0 + wc*64 + ni*16 + (lane & 15)];

    #pragma unroll
    for (int mi = 0; mi < 4; ++mi)
        #pragma unroll
        for (int ni = 0; ni < 4; ++ni) {
            int col = n0 + wc*64 + ni*16 + (lane & 15);
            int rbase = m0 + wr*64 + mi*16 + ((lane>>4)<<2);
            #pragma unroll
            for (int j = 0; j < 4; ++j)
                C[(size_t)(rbase+j)*D_MODEL + col] = acc[mi][ni][j] + bv4[ni];
        }
}

// ---------------------------------------------------------------------------
// Flash attention — round-13 verified body (71 us, 32x32 MFMA, KVB=64).
// ---------------------------------------------------------------------------
#define KVB 64
#define NCH (SEQ/KVB)   // 16
#define THR 8.0f

__global__ __launch_bounds__(256, 3) void attn_flash(
    const unsigned short* __restrict__ Qp,
    const unsigned short* __restrict__ Kp,
    const unsigned short* __restrict__ Vt,
    const float* __restrict__ CW,
    unsigned short* __restrict__ Aop)
{
    __shared__ unsigned short Ks[2][66*64];
    __shared__ unsigned short Vs[2][64*64];

    const int tid = threadIdx.x;
    const int lane = tid & 63, wid = tid >> 6;
    const int ql = lane & 31, g = lane >> 5;

    const int bid = blockIdx.x;
    const int sw = (bid & 7) * 96 + (bid >> 3);
    const int q0 = (sw & 7) * 128;
    const int bh = sw >> 3;
    const int h = bh % NH, b = bh / NH;

    float wcv[9];
    #pragma unroll
    for (int i = 0; i < 9; ++i) wcv[i] = CW[h*9 + i];

    const unsigned short* KpB = Kp + (size_t)b*SEQ*D_MODEL + h*DK;
    const unsigned short* QpB = Qp + (size_t)b*SEQ*D_MODEL + h*DK;
    const char* VtB = (const char*)Vt + (size_t)bh*DK*SEQ*2;

    short8 kreg[3];
    auto kload = [&](int ck) {
        #pragma unroll
        for (int u = 0; u < 3; ++u) {
            int idx = tid + u*256;
            short8 v = (short8)0;
            if (idx < 528) {
                int r = idx >> 3, oct = idx & 7;
                int gk = ck*KVB - 1 + r;
                if (gk >= 0 && gk < SEQ)
                    v = *(const short8*)&KpB[(size_t)gk*D_MODEL + oct*8];
            }
            kreg[u] = v;
        }
    };
    auto kstore = [&](int buf) {
        #pragma unroll
        for (int u = 0; u < 3; ++u) {
            int idx = tid + u*256;
            if (idx < 528) {
                int r = idx >> 3, oct = idx & 7;
                *(short8*)&Ks[buf][r*64 + ((oct ^ (r&7)) << 3)] = kreg[u];
            }
        }
    };
    auto vstage = [&](int ck, int buf) {
        #pragma unroll
        for (int u = 0; u < 2; ++u) {
            int p = (tid + u*256) * 16;
            int row = p >> 7, off = p & 127;
            const char* src = VtB + ((size_t)row*SEQ + ck*KVB)*2 + (off ^ ((row&7)<<4));
            gload_lds16(src, (char*)Vs[buf] + p);
        }
    };

    kload(0);

    short8 qtf[3][4];
    {
        int gq = q0 + wid*32 + ql;
        #pragma unroll
        for (int i = 0; i < 4; ++i) {
            int dwin = i*16 + g*8;
            short8 qm = (short8)0, qc, qp8 = (short8)0;
            if (gq > 0)      qm  = *(const short8*)&QpB[(size_t)(gq-1)*D_MODEL + dwin];
            qc = *(const short8*)&QpB[(size_t)gq*D_MODEL + dwin];
            if (gq < SEQ-1)  qp8 = *(const short8*)&QpB[(size_t)(gq+1)*D_MODEL + dwin];
            short8 f0, f1, f2;
            #pragma unroll
            for (int j = 0; j < 8; ++j) {
                float fm = bf2f((unsigned short)qm[j]);
                float fc = bf2f((unsigned short)qc[j]);
                float fp = bf2f((unsigned short)qp8[j]);
                float t0 = (fc - (wcv[1]*fm + wcv[4]*fc + wcv[7]*fp)) * L2E;
                float t1 = -(wcv[0]*fm + wcv[3]*fc + wcv[6]*fp) * L2E;
                float t2 = -(wcv[2]*fm + wcv[5]*fc + wcv[8]*fp) * L2E;
                f0[j] = (short)f2bf(t0);
                f1[j] = (short)f2bf(t1);
                f2[j] = (short)f2bf(t2);
            }
            qtf[0][i] = f0; qtf[1][i] = f1; qtf[2][i] = f2;
        }
    }
    kstore(0);
    vstage(0, 0);
    __syncthreads();

    float m = -1e30f, l = 0.f;
    f32x16 oac[2];
    oac[0] = (f32x16)(0.f); oac[1] = (f32x16)(0.f);

    int cur = 0;
    for (int ck = 0; ck < NCH; ++ck) {
        if (ck < NCH-1) { kload(ck+1); vstage(ck+1, cur^1); }

        f32x16 st2[2];
        #pragma unroll
        for (int t = 0; t < 2; ++t) {
            f32x16 s = (f32x16)(0.f);
            #pragma unroll
            for (int sl = 0; sl < 3; ++sl) {
                const int shift = (sl == 0) ? 1 : (sl == 1) ? 0 : 2;
                int ar = t*32 + ql + shift;
                #pragma unroll
                for (int i = 0; i < 4; ++i) {
                    int oct = 2*i + g;
                    short8 a = *(const short8*)&Ks[cur][ar*64 + ((oct ^ (ar&7)) << 3)];
                    s = __builtin_amdgcn_mfma_f32_32x32x16_bf16(a, qtf[sl][i], s, 0, 0, 0);
                }
            }
            st2[t] = s;
        }

        float tmax = -1e30f;
        #pragma unroll
        for (int t = 0; t < 2; ++t)
            #pragma unroll
            for (int j = 0; j < 16; ++j) tmax = fmaxf(tmax, st2[t][j]);
        tmax = fmaxf(tmax, __shfl_xor(tmax, 32));

        if (!__all(tmax - m <= THR)) {
            float mn = fmaxf(m, tmax);
            float r = fast_exp2(m - mn);
            l *= r;
            #pragma unroll
            for (int dt = 0; dt < 2; ++dt)
                #pragma unroll
                for (int j = 0; j < 16; ++j) oac[dt][j] *= r;
            m = mn;
        }
        float lsum = 0.f;
        #pragma unroll
        for (int t = 0; t < 2; ++t)
            #pragma unroll
            for (int j = 0; j < 16; ++j) {
                float e = fast_exp2(st2[t][j] - m);
                st2[t][j] = e;
                lsum += e;
            }
        lsum += __shfl_xor(lsum, 32);
        l += lsum;

        short8 pf[4];
        #pragma unroll
        for (int t = 0; t < 2; ++t) {
            #pragma unroll
            for (int f = 0; f < 2; ++f) {
                const int base = f*8;
                unsigned int x0 = pk_bf16_rn(st2[t][base+0], st2[t][base+1]);
                unsigned int x1 = pk_bf16_rn(st2[t][base+2], st2[t][base+3]);
                unsigned int y0 = pk_bf16_rn(st2[t][base+4], st2[t][base+5]);
                unsigned int y1 = pk_bf16_rn(st2[t][base+6], st2[t][base+7]);
                plswap(x0, y0, g);
                plswap(x1, y1, g);
                u32x4 w = {x0, x1, y0, y1};
                pf[t*2 + f] = __builtin_bit_cast(short8, w);
            }
        }

        #pragma unroll
        for (int f = 0; f < 4; ++f) {
            #pragma unroll
            for (int dt = 0; dt < 2; ++dt) {
                int vr = dt*32 + ql;
                int oct = 2*f + g;
                short8 a = *(const short8*)&Vs[cur][vr*64 + ((oct ^ (vr&7)) << 3)];
                oac[dt] = __builtin_amdgcn_mfma_f32_32x32x16_bf16(a, pf[f], oac[dt], 0, 0, 0);
            }
        }

        if (ck < NCH-1) kstore(cur^1);
        __syncthreads();
        cur ^= 1;
    }

    float invl = 1.0f / l;
    int qg = q0 + wid*32 + ql;
    size_t obase = (size_t)(b*SEQ + qg)*D_MODEL + h*DK;
    #pragma unroll
    for (int dt = 0; dt < 2; ++dt) {
        #pragma unroll
        for (int u = 0; u < 4; ++u) {
            int d0 = dt*32 + 8*u + 4*g;
            ushort4v o;
            #pragma unroll
            for (int j = 0; j < 4; ++j) o[j] = f2bf(oac[dt][4*u + j] * invl);
            *(ushort4v*)&Aop[obase + d0] = o;
        }
    }
}

// ---------------------------------------------------------------------------
extern "C" void kernel_launch(void* const* d_in, const int* in_sizes, int n_in,
                              void* d_out, int out_size, void* d_ws, size_t ws_size,
                              hipStream_t stream)
{
    const float* q  = (const float*)d_in[0];
    const float* k  = (const float*)d_in[1];
    const float* v  = (const float*)d_in[2];
    const float* wq = (const float*)d_in[3];
    const float* bq = (const float*)d_in[4];
    const float* wk = (const float*)d_in[5];
    const float* bk = (const float*)d_in[6];
    const float* wv = (const float*)d_in[7];
    const float* bv = (const float*)d_in[8];
    const float* wo = (const float*)d_in[9];
    const float* bo = (const float*)d_in[10];
    const float* cw = (const float*)d_in[11];

    unsigned short* wqb = (unsigned short*)d_ws;
    unsigned short* wkb = wqb + WELT;
    unsigned short* wvb = wkb + WELT;
    unsigned short* wob = wvb + WELT;
    unsigned short* Qp  = wob + WELT;
    unsigned short* Kp  = Qp  + NELT;
    unsigned short* Vtp = Kp  + NELT;
    unsigned short* Aop = Vtp + NELT;

    cvt_w<<<(int)(4*WELT/8/256), 256, 0, stream>>>(wq, wk, wv, wo, wqb, wkb, wvb, wob);

    proj_gemm<<<dim3(1152), 256, 0, stream>>>(q, k, v, wqb, wkb, wvb,
                                              bq, bk, bv, Qp, Kp, Vtp);

    attn_flash<<<dim3(768), 256, 0, stream>>>(Qp, Kp, Vtp, cw, Aop);

    gemm_out<<<dim3(D_MODEL/BN, MTOT/BM), 256, 0, stream>>>(Aop, wob, bo, (float*)d_out);
}

// Round 19
// 147.670 us; speedup vs baseline: 1.7620x; 1.0261x over previous
//
#include <hip/hip_runtime.h>
#include <hip/hip_bf16.h>
#include <math.h>

typedef __attribute__((ext_vector_type(8))) short short8;
typedef __attribute__((ext_vector_type(4))) float f32x4;
typedef __attribute__((ext_vector_type(16))) float f32x16;
typedef __attribute__((ext_vector_type(4))) unsigned short ushort4v;
typedef __attribute__((ext_vector_type(4))) unsigned int u32x4;

#define D_MODEL 768
#define NH      12
#define DK      64
#define SEQ     1024
#define NB      8
#define MTOT    (NB*SEQ)                  // 8192
#define NELT    ((size_t)MTOT*D_MODEL)    // 6291456
#define WELT    ((size_t)D_MODEL*D_MODEL) // 589824
#define L2E     1.44269504088896f

__device__ __forceinline__ unsigned short f2bf(float f) {
    unsigned int u = __builtin_bit_cast(unsigned int, f);
    unsigned int r = (u + 0x7FFFu + ((u >> 16) & 1u)) >> 16;   // RNE
    return (unsigned short)r;
}
__device__ __forceinline__ unsigned short f2bf_rne(float f) {
    __hip_bfloat16 h = __float2bfloat16(f);       // compiler can pair into cvt_pk
    return __builtin_bit_cast(unsigned short, h);
}
__device__ __forceinline__ float bf2f(unsigned short h) {
    return __builtin_bit_cast(float, ((unsigned int)h) << 16);
}
__device__ __forceinline__ float fast_exp2(float x) {
#if __has_builtin(__builtin_amdgcn_exp2f)
    return __builtin_amdgcn_exp2f(x);        // bare v_exp_f32
#else
    return __expf(x * 0.69314718056f);
#endif
}
// pack two floats -> two bf16 (round-nearest) in one u32: {hi.bf16, lo.bf16}
__device__ __forceinline__ unsigned int pk_bf16_rn(float lo, float hi) {
    unsigned int ul = __builtin_bit_cast(unsigned int, lo) + 0x8000u;
    unsigned int uh = __builtin_bit_cast(unsigned int, hi) + 0x8000u;
    return __builtin_amdgcn_perm(uh, ul, 0x07060302u);  // {uh[3:2], ul[3:2]}
}
// v_permlane32_swap semantics: a.upper32lanes <-> b.lower32lanes
__device__ __forceinline__ void plswap(unsigned int &a, unsigned int &b, int g) {
#if __has_builtin(__builtin_amdgcn_permlane32_swap)
    typedef __attribute__((ext_vector_type(2))) unsigned int uint2v;
    uint2v r = __builtin_amdgcn_permlane32_swap(a, b, false, false);
    a = r[0]; b = r[1];
#else
    unsigned int sa = __shfl_xor(a, 32), sb = __shfl_xor(b, 32);
    unsigned int na = g ? sb : a;
    unsigned int nb = g ? b : sa;
    a = na; b = nb;
#endif
}
__device__ __forceinline__ void gload_lds16(const void* g, void* lds) {
    __builtin_amdgcn_global_load_lds(
        (const __attribute__((address_space(1))) unsigned int*)g,
        (__attribute__((address_space(3))) unsigned int*)lds, 16, 0, 0);
}

// ---------------------------------------------------------------------------
// fp32 -> bf16 convert: the 4 weight matrices only (small)
// ---------------------------------------------------------------------------
__global__ __launch_bounds__(256) void cvt_w(
    const float* __restrict__ a, const float* __restrict__ b,
    const float* __restrict__ c, const float* __restrict__ e,
    unsigned short* __restrict__ oa, unsigned short* __restrict__ ob,
    unsigned short* __restrict__ oc, unsigned short* __restrict__ oe)
{
    size_t i = (size_t)blockIdx.x * 256 + threadIdx.x;
    const size_t per = WELT / 8;
    const float* s; unsigned short* d; size_t l;
    if (i < per)        { s = a; d = oa; l = i; }
    else if (i < 2*per) { s = b; d = ob; l = i - per; }
    else if (i < 3*per) { s = c; d = oc; l = i - 2*per; }
    else                { s = e; d = oe; l = i - 3*per; }
    const float4* sp = (const float4*)(s + l*8);
    float4 v0 = sp[0], v1 = sp[1];
    short8 o;
    o[0]=(short)f2bf(v0.x); o[1]=(short)f2bf(v0.y); o[2]=(short)f2bf(v0.z); o[3]=(short)f2bf(v0.w);
    o[4]=(short)f2bf(v1.x); o[5]=(short)f2bf(v1.y); o[6]=(short)f2bf(v1.z); o[7]=(short)f2bf(v1.w);
    *(short8*)(d + l*8) = o;
}

// ---------------------------------------------------------------------------
// Merged projection GEMM, fp32 A direct via global_load_lds, BKP=32,
// double-buffered stage-ahead (round-18 wall-best variant).
// z = 0: Qp = (q@wq^T + bq)*0.125   z = 1: Kp   z = 2: Vt (transposed)
// ---------------------------------------------------------------------------
#define BM 128
#define BN 128
#define BKG 64   // used by gemm_out only
#define BKP 32   // proj K-step
#define NKP (D_MODEL/BKP)   // 24

__global__ __launch_bounds__(256, 3) void proj_gemm(
    const float* __restrict__ Aq, const float* __restrict__ Ak, const float* __restrict__ Av,
    const unsigned short* __restrict__ Wq, const unsigned short* __restrict__ Wk,
    const unsigned short* __restrict__ Wv,
    const float* __restrict__ bq, const float* __restrict__ bk, const float* __restrict__ bv,
    unsigned short* __restrict__ Qp, unsigned short* __restrict__ Kp,
    unsigned short* __restrict__ Vtp)
{
    __shared__ float Asf[2][BM*BKP];           // 2 x 16 KB
    __shared__ unsigned short Bs[2][BN*BKP];   // 2 x 8 KB
    const int tid = threadIdx.x;
    const int lane = tid & 63, wid = tid >> 6;
    const int wr = wid >> 1, wc = wid & 1;

    const int bid = blockIdx.x;
    const int xcd = bid & 7;
    const int j = bid >> 3;
    const int mzL = j / 6, n = j % 6;
    const int mz = xcd * 24 + mzL;
    const int z = mz >> 6;
    const int m0 = (mz & 63) * BM, n0 = n * BN;

    const float* A          = (z == 0) ? Aq : (z == 1) ? Ak : Av;
    const unsigned short* W = (z == 0) ? Wq : (z == 1) ? Wk : Wv;
    const float* bias       = (z == 0) ? bq : (z == 1) ? bk : bv;

    f32x4 acc[4][4];
    #pragma unroll
    for (int i = 0; i < 4; ++i)
        #pragma unroll
        for (int jj = 0; jj < 4; ++jj) acc[i][jj] = (f32x4)(0.f);

    auto stage = [&](int buf, int k0) {
        #pragma unroll
        for (int c = 0; c < 4; ++c) {
            int chunk = wid*4 + c;
            int gI = (chunk << 6) + lane;
            int row = gI >> 3, gran = gI & 7;
            const float* srcA = A + (size_t)(m0+row)*D_MODEL + k0 + ((gran ^ (row & 7)) << 2);
            gload_lds16(srcA, (char*)Asf[buf] + (chunk << 10));
        }
        #pragma unroll
        for (int c = 0; c < 2; ++c) {
            int chunk = wid*2 + c;
            int gI = (chunk << 6) + lane;
            int row = gI >> 2, oct = gI & 3;
            const unsigned short* srcB = W + (size_t)(n0+row)*D_MODEL + k0
                                           + ((oct ^ ((row >> 1) & 3)) << 3);
            gload_lds16(srcB, (char*)Bs[buf] + (chunk << 10));
        }
    };

    stage(0, 0);
    __syncthreads();
    int buf = 0;
    for (int t = 0; t < NKP; ++t) {
        if (t + 1 < NKP) stage(buf ^ 1, (t + 1) * BKP);
        {
            short8 af[4], bf8[4];
            const int g = lane >> 4;
            #pragma unroll
            for (int mi = 0; mi < 4; ++mi) {
                int row = wr*64 + mi*16 + (lane & 15);
                int g0 = 2*g;
                const float* r0 = Asf[buf] + row*8*4 + (((g0  ) ^ (row & 7)) << 2);
                const float* r1 = Asf[buf] + row*8*4 + (((g0+1) ^ (row & 7)) << 2);
                float4 a0 = *(const float4*)r0;
                float4 a1 = *(const float4*)r1;
                short8 v;
                v[0]=(short)f2bf_rne(a0.x); v[1]=(short)f2bf_rne(a0.y);
                v[2]=(short)f2bf_rne(a0.z); v[3]=(short)f2bf_rne(a0.w);
                v[4]=(short)f2bf_rne(a1.x); v[5]=(short)f2bf_rne(a1.y);
                v[6]=(short)f2bf_rne(a1.z); v[7]=(short)f2bf_rne(a1.w);
                af[mi] = v;
            }
            #pragma unroll
            for (int ni = 0; ni < 4; ++ni) {
                int row = wc*64 + ni*16 + (lane & 15);
                bf8[ni] = *(const short8*)&Bs[buf][row*BKP + ((g ^ ((row >> 1) & 3)) << 3)];
            }
            #pragma unroll
            for (int mi = 0; mi < 4; ++mi)
                #pragma unroll
                for (int ni = 0; ni < 4; ++ni)
                    acc[mi][ni] = __builtin_amdgcn_mfma_f32_16x16x32_bf16(af[mi], bf8[ni], acc[mi][ni], 0, 0, 0);
        }
        __syncthreads();
        buf ^= 1;
    }

    float bv4[4];
    #pragma unroll
    for (int ni = 0; ni < 4; ++ni) bv4[ni] = bias[n0 + wc*64 + ni*16 + (lane & 15)];

    if (z < 2) {
        unsigned short* C = (z == 0) ? Qp : Kp;
        const float scale = (z == 0) ? 0.125f : 1.0f;
        #pragma unroll
        for (int mi = 0; mi < 4; ++mi)
            #pragma unroll
            for (int ni = 0; ni < 4; ++ni) {
                int col = n0 + wc*64 + ni*16 + (lane & 15);
                int rbase = m0 + wr*64 + mi*16 + ((lane>>4)<<2);
                #pragma unroll
                for (int jj = 0; jj < 4; ++jj)
                    C[(size_t)(rbase+jj)*D_MODEL + col] = f2bf((acc[mi][ni][jj] + bv4[ni]) * scale);
            }
    } else {
        #pragma unroll
        for (int mi = 0; mi < 4; ++mi)
            #pragma unroll
            for (int ni = 0; ni < 4; ++ni) {
                int col = n0 + wc*64 + ni*16 + (lane & 15);
                int hh = col >> 6, dd = col & 63;
                int mrow = m0 + wr*64 + mi*16 + ((lane>>4)<<2);
                int bb = mrow >> 10, ss = mrow & (SEQ-1);
                ushort4v pk;
                #pragma unroll
                for (int jj = 0; jj < 4; ++jj) pk[jj] = f2bf(acc[mi][ni][jj] + bv4[ni]);
                *(ushort4v*)&Vtp[((size_t)(bb*NH + hh)*DK + dd)*SEQ + ss] = pk;
            }
    }
}

// ---------------------------------------------------------------------------
// Final GEMM: out_fp32 = Aop(bf16) @ wo^T + bo
// ---------------------------------------------------------------------------
__global__ __launch_bounds__(256) void gemm_out(
    const unsigned short* __restrict__ A, const unsigned short* __restrict__ W,
    const float* __restrict__ bias, float* __restrict__ C)
{
    __shared__ unsigned short As[BM*BKG];
    __shared__ unsigned short Bs[BN*BKG];
    const int tid = threadIdx.x;
    const int lane = tid & 63, wid = tid >> 6;
    const int wr = wid >> 1, wc = wid & 1;
    const int m0 = blockIdx.y * BM, n0 = blockIdx.x * BN;

    f32x4 acc[4][4];
    #pragma unroll
    for (int i = 0; i < 4; ++i)
        #pragma unroll
        for (int j = 0; j < 4; ++j) acc[i][j] = (f32x4)(0.f);

    for (int k0 = 0; k0 < D_MODEL; k0 += BKG) {
        __syncthreads();
        #pragma unroll
        for (int j = 0; j < 4; ++j) {
            int p = ((wid*4 + j) << 9) + lane*8;
            int row = p >> 6, off = p & 63;
            const unsigned short* srcA = A + (size_t)(m0+row)*D_MODEL + k0 + (off ^ ((row&7)<<3));
            gload_lds16(srcA, &As[(wid*4 + j) << 9]);
            const unsigned short* srcB = W + (size_t)(n0+row)*D_MODEL + k0 + (off ^ ((row&7)<<3));
            gload_lds16(srcB, &Bs[(wid*4 + j) << 9]);
        }
        __syncthreads();
        #pragma unroll
        for (int ks = 0; ks < 2; ++ks) {
            short8 af[4], bf8[4];
            #pragma unroll
            for (int mi = 0; mi < 4; ++mi) {
                int row = wr*64 + mi*16 + (lane & 15);
                af[mi] = *(const short8*)&As[row*BKG + ((ks*32 + (lane>>4)*8) ^ ((row&7)<<3))];
            }
            #pragma unroll
            for (int ni = 0; ni < 4; ++ni) {
                int row = wc*64 + ni*16 + (lane & 15);
                bf8[ni] = *(const short8*)&Bs[row*BKG + ((ks*32 + (lane>>4)*8) ^ ((row&7)<<3))];
            }
            #pragma unroll
            for (int mi = 0; mi < 4; ++mi)
                #pragma unroll
                for (int ni = 0; ni < 4; ++ni)
                    acc[mi][ni] = __builtin_amdgcn_mfma_f32_16x16x32_bf16(af[mi], bf8[ni], acc[mi][ni], 0, 0, 0);
        }
    }

    float bv4[4];
    #pragma unroll
    for (int ni = 0; ni < 4; ++ni) bv4[ni] = bias[n0 + wc*64 + ni*16 + (lane & 15)];

    #pragma unroll
    for (int mi = 0; mi < 4; ++mi)
        #pragma unroll
        for (int ni = 0; ni < 4; ++ni) {
            int col = n0 + wc*64 + ni*16 + (lane & 15);
            int rbase = m0 + wr*64 + mi*16 + ((lane>>4)<<2);
            #pragma unroll
            for (int j = 0; j < 4; ++j)
                C[(size_t)(rbase+j)*D_MODEL + col] = acc[mi][ni][j] + bv4[ni];
        }
}

// ---------------------------------------------------------------------------
// Flash attention, 32x32 MFMA, KVB=64. K interior rows via global_load_lds
// (pre-swizzled source, linear dest); only the 2 halo rows go through regs.
// ---------------------------------------------------------------------------
#define KVB 64
#define NCH (SEQ/KVB)   // 16
#define THR 8.0f

__global__ __launch_bounds__(256, 3) void attn_flash(
    const unsigned short* __restrict__ Qp,
    const unsigned short* __restrict__ Kp,
    const unsigned short* __restrict__ Vt,
    const float* __restrict__ CW,
    unsigned short* __restrict__ Aop)
{
    __shared__ unsigned short Ks[2][66*64];  // rows 0..65 = keys ck*64-1..+64
    __shared__ unsigned short Vs[2][64*64];

    const int tid = threadIdx.x;
    const int lane = tid & 63, wid = tid >> 6;
    const int ql = lane & 31, g = lane >> 5;

    const int bid = blockIdx.x;
    const int sw = (bid & 7) * 96 + (bid >> 3);
    const int q0 = (sw & 7) * 128;
    const int bh = sw >> 3;
    const int h = bh % NH, b = bh / NH;

    float wcv[9];
    #pragma unroll
    for (int i = 0; i < 9; ++i) wcv[i] = CW[h*9 + i];

    const unsigned short* KpB = Kp + (size_t)b*SEQ*D_MODEL + h*DK;
    const unsigned short* QpB = Qp + (size_t)b*SEQ*D_MODEL + h*DK;
    const char* VtB = (const char*)Vt + (size_t)bh*DK*SEQ*2;

    // ---- K interior rows 1..64 (keys ck*64..+63) via gload_lds ----
    auto kstage = [&](int ck, int buf) {
        #pragma unroll
        for (int u = 0; u < 2; ++u) {
            int p = (tid + u*256) * 16;          // byte pos in 8 KB interior
            int row = p >> 7, off = p & 127;     // row 0..63 -> LDS row row+1
            const char* src = (const char*)KpB
                + ((size_t)(ck*KVB + row)*D_MODEL)*2 + (off ^ (((row+1)&7)<<4));
            gload_lds16(src, (char*)Ks[buf] + 128 + p);
        }
    };
    // ---- halo rows 0 (key ck*64-1) and 65 (key ck*64+64), tid<16, regs ----
    short8 khreg;
    auto khalo_load = [&](int ck) {
        if (tid < 16) {
            int r = (tid >> 3) ? 65 : 0;
            int oct = tid & 7;
            int gk = ck*KVB - 1 + r;
            short8 v = (short8)0;
            if (gk >= 0 && gk < SEQ) v = *(const short8*)&KpB[(size_t)gk*D_MODEL + oct*8];
            khreg = v;
        }
    };
    auto khalo_store = [&](int buf) {
        if (tid < 16) {
            int r = (tid >> 3) ? 65 : 0;
            int oct = tid & 7;
            *(short8*)&Ks[buf][r*64 + ((oct ^ (r&7)) << 3)] = khreg;
        }
    };
    auto vstage = [&](int ck, int buf) {
        #pragma unroll
        for (int u = 0; u < 2; ++u) {
            int p = (tid + u*256) * 16;
            int row = p >> 7, off = p & 127;
            const char* src = VtB + ((size_t)row*SEQ + ck*KVB)*2 + (off ^ ((row&7)<<4));
            gload_lds16(src, (char*)Vs[buf] + p);
        }
    };

    khalo_load(0);

    short8 qtf[3][4];
    {
        int gq = q0 + wid*32 + ql;
        #pragma unroll
        for (int i = 0; i < 4; ++i) {
            int dwin = i*16 + g*8;
            short8 qm = (short8)0, qc, qp8 = (short8)0;
            if (gq > 0)      qm  = *(const short8*)&QpB[(size_t)(gq-1)*D_MODEL + dwin];
            qc = *(const short8*)&QpB[(size_t)gq*D_MODEL + dwin];
            if (gq < SEQ-1)  qp8 = *(const short8*)&QpB[(size_t)(gq+1)*D_MODEL + dwin];
            short8 f0, f1, f2;
            #pragma unroll
            for (int j = 0; j < 8; ++j) {
                float fm = bf2f((unsigned short)qm[j]);
                float fc = bf2f((unsigned short)qc[j]);
                float fp = bf2f((unsigned short)qp8[j]);
                float t0 = (fc - (wcv[1]*fm + wcv[4]*fc + wcv[7]*fp)) * L2E;
                float t1 = -(wcv[0]*fm + wcv[3]*fc + wcv[6]*fp) * L2E;
                float t2 = -(wcv[2]*fm + wcv[5]*fc + wcv[8]*fp) * L2E;
                f0[j] = (short)f2bf(t0);
                f1[j] = (short)f2bf(t1);
                f2[j] = (short)f2bf(t2);
            }
            qtf[0][i] = f0; qtf[1][i] = f1; qtf[2][i] = f2;
        }
    }
    khalo_store(0);
    kstage(0, 0);
    vstage(0, 0);
    __syncthreads();

    float m = -1e30f, l = 0.f;
    f32x16 oac[2];
    oac[0] = (f32x16)(0.f); oac[1] = (f32x16)(0.f);

    int cur = 0;
    for (int ck = 0; ck < NCH; ++ck) {
        if (ck < NCH-1) {
            khalo_load(ck+1);          // global loads fly under QK phase
            kstage(ck+1, cur^1);       // direct-to-LDS, drained at barrier
            vstage(ck+1, cur^1);
        }

        f32x16 st2[2];
        #pragma unroll
        for (int t = 0; t < 2; ++t) {
            f32x16 s = (f32x16)(0.f);
            #pragma unroll
            for (int sl = 0; sl < 3; ++sl) {
                const int shift = (sl == 0) ? 1 : (sl == 1) ? 0 : 2;
                int ar = t*32 + ql + shift;
                #pragma unroll
                for (int i = 0; i < 4; ++i) {
                    int oct = 2*i + g;
                    short8 a = *(const short8*)&Ks[cur][ar*64 + ((oct ^ (ar&7)) << 3)];
                    s = __builtin_amdgcn_mfma_f32_32x32x16_bf16(a, qtf[sl][i], s, 0, 0, 0);
                }
            }
            st2[t] = s;
        }

        float tmax = -1e30f;
        #pragma unroll
        for (int t = 0; t < 2; ++t)
            #pragma unroll
            for (int j = 0; j < 16; ++j) tmax = fmaxf(tmax, st2[t][j]);
        tmax = fmaxf(tmax, __shfl_xor(tmax, 32));

        if (!__all(tmax - m <= THR)) {
            float mn = fmaxf(m, tmax);
            float r = fast_exp2(m - mn);
            l *= r;
            #pragma unroll
            for (int dt = 0; dt < 2; ++dt)
                #pragma unroll
                for (int j = 0; j < 16; ++j) oac[dt][j] *= r;
            m = mn;
        }
        float lsum = 0.f;
        #pragma unroll
        for (int t = 0; t < 2; ++t)
            #pragma unroll
            for (int j = 0; j < 16; ++j) {
                float e = fast_exp2(st2[t][j] - m);
                st2[t][j] = e;
                lsum += e;
            }
        lsum += __shfl_xor(lsum, 32);
        l += lsum;

        short8 pf[4];
        #pragma unroll
        for (int t = 0; t < 2; ++t) {
            #pragma unroll
            for (int f = 0; f < 2; ++f) {
                const int base = f*8;
                unsigned int x0 = pk_bf16_rn(st2[t][base+0], st2[t][base+1]);
                unsigned int x1 = pk_bf16_rn(st2[t][base+2], st2[t][base+3]);
                unsigned int y0 = pk_bf16_rn(st2[t][base+4], st2[t][base+5]);
                unsigned int y1 = pk_bf16_rn(st2[t][base+6], st2[t][base+7]);
                plswap(x0, y0, g);
                plswap(x1, y1, g);
                u32x4 w = {x0, x1, y0, y1};
                pf[t*2 + f] = __builtin_bit_cast(short8, w);
            }
        }

        #pragma unroll
        for (int f = 0; f < 4; ++f) {
            #pragma unroll
            for (int dt = 0; dt < 2; ++dt) {
                int vr = dt*32 + ql;
                int oct = 2*f + g;
                short8 a = *(const short8*)&Vs[cur][vr*64 + ((oct ^ (vr&7)) << 3)];
                oac[dt] = __builtin_amdgcn_mfma_f32_32x32x16_bf16(a, pf[f], oac[dt], 0, 0, 0);
            }
        }

        if (ck < NCH-1) khalo_store(cur^1);
        __syncthreads();   // drains gload_lds (K interior + V) + orders halo write
        cur ^= 1;
    }

    float invl = 1.0f / l;
    int qg = q0 + wid*32 + ql;
    size_t obase = (size_t)(b*SEQ + qg)*D_MODEL + h*DK;
    #pragma unroll
    for (int dt = 0; dt < 2; ++dt) {
        #pragma unroll
        for (int u = 0; u < 4; ++u) {
            int d0 = dt*32 + 8*u + 4*g;
            ushort4v o;
            #pragma unroll
            for (int j = 0; j < 4; ++j) o[j] = f2bf(oac[dt][4*u + j] * invl);
            *(ushort4v*)&Aop[obase + d0] = o;
        }
    }
}

// ---------------------------------------------------------------------------
extern "C" void kernel_launch(void* const* d_in, const int* in_sizes, int n_in,
                              void* d_out, int out_size, void* d_ws, size_t ws_size,
                              hipStream_t stream)
{
    const float* q  = (const float*)d_in[0];
    const float* k  = (const float*)d_in[1];
    const float* v  = (const float*)d_in[2];
    const float* wq = (const float*)d_in[3];
    const float* bq = (const float*)d_in[4];
    const float* wk = (const float*)d_in[5];
    const float* bk = (const float*)d_in[6];
    const float* wv = (const float*)d_in[7];
    const float* bv = (const float*)d_in[8];
    const float* wo = (const float*)d_in[9];
    const float* bo = (const float*)d_in[10];
    const float* cw = (const float*)d_in[11];

    unsigned short* wqb = (unsigned short*)d_ws;
    unsigned short* wkb = wqb + WELT;
    unsigned short* wvb = wkb + WELT;
    unsigned short* wob = wvb + WELT;
    unsigned short* Qp  = wob + WELT;
    unsigned short* Kp  = Qp  + NELT;
    unsigned short* Vtp = Kp  + NELT;
    unsigned short* Aop = Vtp + NELT;

    cvt_w<<<(int)(4*WELT/8/256), 256, 0, stream>>>(wq, wk, wv, wo, wqb, wkb, wvb, wob);

    proj_gemm<<<dim3(1152), 256, 0, stream>>>(q, k, v, wqb, wkb, wvb,
                                              bq, bk, bv, Qp, Kp, Vtp);

    attn_flash<<<dim3(768), 256, 0, stream>>>(Qp, Kp, Vtp, cw, Aop);

    gemm_out<<<dim3(D_MODEL/BN, MTOT/BM), 256, 0, stream>>>(Aop, wob, bo, (float*)d_out);
}

// Round 20
// 146.355 us; speedup vs baseline: 1.7778x; 1.0090x over previous
//
#include <hip/hip_runtime.h>
#include <hip/hip_bf16.h>
#include <math.h>

typedef __attribute__((ext_vector_type(8))) short short8;
typedef __attribute__((ext_vector_type(4))) float f32x4;
typedef __attribute__((ext_vector_type(16))) float f32x16;
typedef __attribute__((ext_vector_type(4))) unsigned short ushort4v;
typedef __attribute__((ext_vector_type(4))) unsigned int u32x4;

#define D_MODEL 768
#define NH      12
#define DK      64
#define SEQ     1024
#define NB      8
#define MTOT    (NB*SEQ)                  // 8192
#define NELT    ((size_t)MTOT*D_MODEL)    // 6291456
#define WELT    ((size_t)D_MODEL*D_MODEL) // 589824
#define L2E     1.44269504088896f

__device__ __forceinline__ unsigned short f2bf(float f) {
    unsigned int u = __builtin_bit_cast(unsigned int, f);
    unsigned int r = (u + 0x7FFFu + ((u >> 16) & 1u)) >> 16;   // RNE
    return (unsigned short)r;
}
__device__ __forceinline__ unsigned short f2bf_rne(float f) {
    __hip_bfloat16 h = __float2bfloat16(f);       // compiler can pair into cvt_pk
    return __builtin_bit_cast(unsigned short, h);
}
__device__ __forceinline__ float bf2f(unsigned short h) {
    return __builtin_bit_cast(float, ((unsigned int)h) << 16);
}
__device__ __forceinline__ float fast_exp2(float x) {
#if __has_builtin(__builtin_amdgcn_exp2f)
    return __builtin_amdgcn_exp2f(x);        // bare v_exp_f32
#else
    return __expf(x * 0.69314718056f);
#endif
}
// pack two floats -> two bf16 (round-nearest) in one u32: {hi.bf16, lo.bf16}
__device__ __forceinline__ unsigned int pk_bf16_rn(float lo, float hi) {
    unsigned int ul = __builtin_bit_cast(unsigned int, lo) + 0x8000u;
    unsigned int uh = __builtin_bit_cast(unsigned int, hi) + 0x8000u;
    return __builtin_amdgcn_perm(uh, ul, 0x07060302u);  // {uh[3:2], ul[3:2]}
}
// v_permlane32_swap semantics: a.upper32lanes <-> b.lower32lanes
__device__ __forceinline__ void plswap(unsigned int &a, unsigned int &b, int g) {
#if __has_builtin(__builtin_amdgcn_permlane32_swap)
    typedef __attribute__((ext_vector_type(2))) unsigned int uint2v;
    uint2v r = __builtin_amdgcn_permlane32_swap(a, b, false, false);
    a = r[0]; b = r[1];
#else
    unsigned int sa = __shfl_xor(a, 32), sb = __shfl_xor(b, 32);
    unsigned int na = g ? sb : a;
    unsigned int nb = g ? b : sa;
    a = na; b = nb;
#endif
}
__device__ __forceinline__ void gload_lds16(const void* g, void* lds) {
    __builtin_amdgcn_global_load_lds(
        (const __attribute__((address_space(1))) unsigned int*)g,
        (__attribute__((address_space(3))) unsigned int*)lds, 16, 0, 0);
}

// ---------------------------------------------------------------------------
// fp32 -> bf16 convert: the 4 weight matrices only (small)
// ---------------------------------------------------------------------------
__global__ __launch_bounds__(256) void cvt_w(
    const float* __restrict__ a, const float* __restrict__ b,
    const float* __restrict__ c, const float* __restrict__ e,
    unsigned short* __restrict__ oa, unsigned short* __restrict__ ob,
    unsigned short* __restrict__ oc, unsigned short* __restrict__ oe)
{
    size_t i = (size_t)blockIdx.x * 256 + threadIdx.x;
    const size_t per = WELT / 8;
    const float* s; unsigned short* d; size_t l;
    if (i < per)        { s = a; d = oa; l = i; }
    else if (i < 2*per) { s = b; d = ob; l = i - per; }
    else if (i < 3*per) { s = c; d = oc; l = i - 2*per; }
    else                { s = e; d = oe; l = i - 3*per; }
    const float4* sp = (const float4*)(s + l*8);
    float4 v0 = sp[0], v1 = sp[1];
    short8 o;
    o[0]=(short)f2bf(v0.x); o[1]=(short)f2bf(v0.y); o[2]=(short)f2bf(v0.z); o[3]=(short)f2bf(v0.w);
    o[4]=(short)f2bf(v1.x); o[5]=(short)f2bf(v1.y); o[6]=(short)f2bf(v1.z); o[7]=(short)f2bf(v1.w);
    *(short8*)(d + l*8) = o;
}

// ---------------------------------------------------------------------------
// Merged projection GEMM, fp32 A direct via global_load_lds, BKP=32,
// double-buffered stage-ahead (round-18/19 verified variant).
// z = 0: Qp = (q@wq^T + bq)*0.125   z = 1: Kp   z = 2: Vt (transposed)
// ---------------------------------------------------------------------------
#define BM 128
#define BN 128
#define BKG 64   // used by gemm_out only
#define BKP 32   // proj K-step
#define NKP (D_MODEL/BKP)   // 24

__global__ __launch_bounds__(256, 3) void proj_gemm(
    const float* __restrict__ Aq, const float* __restrict__ Ak, const float* __restrict__ Av,
    const unsigned short* __restrict__ Wq, const unsigned short* __restrict__ Wk,
    const unsigned short* __restrict__ Wv,
    const float* __restrict__ bq, const float* __restrict__ bk, const float* __restrict__ bv,
    unsigned short* __restrict__ Qp, unsigned short* __restrict__ Kp,
    unsigned short* __restrict__ Vtp)
{
    __shared__ float Asf[2][BM*BKP];           // 2 x 16 KB
    __shared__ unsigned short Bs[2][BN*BKP];   // 2 x 8 KB
    const int tid = threadIdx.x;
    const int lane = tid & 63, wid = tid >> 6;
    const int wr = wid >> 1, wc = wid & 1;

    const int bid = blockIdx.x;
    const int xcd = bid & 7;
    const int j = bid >> 3;
    const int mzL = j / 6, n = j % 6;
    const int mz = xcd * 24 + mzL;
    const int z = mz >> 6;
    const int m0 = (mz & 63) * BM, n0 = n * BN;

    const float* A          = (z == 0) ? Aq : (z == 1) ? Ak : Av;
    const unsigned short* W = (z == 0) ? Wq : (z == 1) ? Wk : Wv;
    const float* bias       = (z == 0) ? bq : (z == 1) ? bk : bv;

    f32x4 acc[4][4];
    #pragma unroll
    for (int i = 0; i < 4; ++i)
        #pragma unroll
        for (int jj = 0; jj < 4; ++jj) acc[i][jj] = (f32x4)(0.f);

    auto stage = [&](int buf, int k0) {
        #pragma unroll
        for (int c = 0; c < 4; ++c) {
            int chunk = wid*4 + c;
            int gI = (chunk << 6) + lane;
            int row = gI >> 3, gran = gI & 7;
            const float* srcA = A + (size_t)(m0+row)*D_MODEL + k0 + ((gran ^ (row & 7)) << 2);
            gload_lds16(srcA, (char*)Asf[buf] + (chunk << 10));
        }
        #pragma unroll
        for (int c = 0; c < 2; ++c) {
            int chunk = wid*2 + c;
            int gI = (chunk << 6) + lane;
            int row = gI >> 2, oct = gI & 3;
            const unsigned short* srcB = W + (size_t)(n0+row)*D_MODEL + k0
                                           + ((oct ^ ((row >> 1) & 3)) << 3);
            gload_lds16(srcB, (char*)Bs[buf] + (chunk << 10));
        }
    };

    stage(0, 0);
    __syncthreads();
    int buf = 0;
    for (int t = 0; t < NKP; ++t) {
        if (t + 1 < NKP) stage(buf ^ 1, (t + 1) * BKP);
        {
            short8 af[4], bf8[4];
            const int g = lane >> 4;
            #pragma unroll
            for (int mi = 0; mi < 4; ++mi) {
                int row = wr*64 + mi*16 + (lane & 15);
                int g0 = 2*g;
                const float* r0 = Asf[buf] + row*8*4 + (((g0  ) ^ (row & 7)) << 2);
                const float* r1 = Asf[buf] + row*8*4 + (((g0+1) ^ (row & 7)) << 2);
                float4 a0 = *(const float4*)r0;
                float4 a1 = *(const float4*)r1;
                short8 v;
                v[0]=(short)f2bf_rne(a0.x); v[1]=(short)f2bf_rne(a0.y);
                v[2]=(short)f2bf_rne(a0.z); v[3]=(short)f2bf_rne(a0.w);
                v[4]=(short)f2bf_rne(a1.x); v[5]=(short)f2bf_rne(a1.y);
                v[6]=(short)f2bf_rne(a1.z); v[7]=(short)f2bf_rne(a1.w);
                af[mi] = v;
            }
            #pragma unroll
            for (int ni = 0; ni < 4; ++ni) {
                int row = wc*64 + ni*16 + (lane & 15);
                bf8[ni] = *(const short8*)&Bs[buf][row*BKP + ((g ^ ((row >> 1) & 3)) << 3)];
            }
            #pragma unroll
            for (int mi = 0; mi < 4; ++mi)
                #pragma unroll
                for (int ni = 0; ni < 4; ++ni)
                    acc[mi][ni] = __builtin_amdgcn_mfma_f32_16x16x32_bf16(af[mi], bf8[ni], acc[mi][ni], 0, 0, 0);
        }
        __syncthreads();
        buf ^= 1;
    }

    float bv4[4];
    #pragma unroll
    for (int ni = 0; ni < 4; ++ni) bv4[ni] = bias[n0 + wc*64 + ni*16 + (lane & 15)];

    if (z < 2) {
        unsigned short* C = (z == 0) ? Qp : Kp;
        const float scale = (z == 0) ? 0.125f : 1.0f;
        #pragma unroll
        for (int mi = 0; mi < 4; ++mi)
            #pragma unroll
            for (int ni = 0; ni < 4; ++ni) {
                int col = n0 + wc*64 + ni*16 + (lane & 15);
                int rbase = m0 + wr*64 + mi*16 + ((lane>>4)<<2);
                #pragma unroll
                for (int jj = 0; jj < 4; ++jj)
                    C[(size_t)(rbase+jj)*D_MODEL + col] = f2bf((acc[mi][ni][jj] + bv4[ni]) * scale);
            }
    } else {
        #pragma unroll
        for (int mi = 0; mi < 4; ++mi)
            #pragma unroll
            for (int ni = 0; ni < 4; ++ni) {
                int col = n0 + wc*64 + ni*16 + (lane & 15);
                int hh = col >> 6, dd = col & 63;
                int mrow = m0 + wr*64 + mi*16 + ((lane>>4)<<2);
                int bb = mrow >> 10, ss = mrow & (SEQ-1);
                ushort4v pk;
                #pragma unroll
                for (int jj = 0; jj < 4; ++jj) pk[jj] = f2bf(acc[mi][ni][jj] + bv4[ni]);
                *(ushort4v*)&Vtp[((size_t)(bb*NH + hh)*DK + dd)*SEQ + ss] = pk;
            }
    }
}

// ---------------------------------------------------------------------------
// Final GEMM: out_fp32 = Aop(bf16) @ wo^T + bo.
// XCD-grouped 1D grid: 384 = 8 xcd x 8 m-tiles x 6 n (n fastest) so the 6
// n-consumers of each Aop m-panel share one XCD's L2.
// ---------------------------------------------------------------------------
__global__ __launch_bounds__(256) void gemm_out(
    const unsigned short* __restrict__ A, const unsigned short* __restrict__ W,
    const float* __restrict__ bias, float* __restrict__ C)
{
    __shared__ unsigned short As[BM*BKG];
    __shared__ unsigned short Bs[BN*BKG];
    const int tid = threadIdx.x;
    const int lane = tid & 63, wid = tid >> 6;
    const int wr = wid >> 1, wc = wid & 1;

    const int bid = blockIdx.x;
    const int xcd = bid & 7;
    const int j = bid >> 3;          // 0..47
    const int mL = j / 6, n = j % 6;
    const int m0 = (xcd * 8 + mL) * BM, n0 = n * BN;

    f32x4 acc[4][4];
    #pragma unroll
    for (int i = 0; i < 4; ++i)
        #pragma unroll
        for (int jj = 0; jj < 4; ++jj) acc[i][jj] = (f32x4)(0.f);

    for (int k0 = 0; k0 < D_MODEL; k0 += BKG) {
        __syncthreads();
        #pragma unroll
        for (int jj = 0; jj < 4; ++jj) {
            int p = ((wid*4 + jj) << 9) + lane*8;
            int row = p >> 6, off = p & 63;
            const unsigned short* srcA = A + (size_t)(m0+row)*D_MODEL + k0 + (off ^ ((row&7)<<3));
            gload_lds16(srcA, &As[(wid*4 + jj) << 9]);
            const unsigned short* srcB = W + (size_t)(n0+row)*D_MODEL + k0 + (off ^ ((row&7)<<3));
            gload_lds16(srcB, &Bs[(wid*4 + jj) << 9]);
        }
        __syncthreads();
        #pragma unroll
        for (int ks = 0; ks < 2; ++ks) {
            short8 af[4], bf8[4];
            #pragma unroll
            for (int mi = 0; mi < 4; ++mi) {
                int row = wr*64 + mi*16 + (lane & 15);
                af[mi] = *(const short8*)&As[row*BKG + ((ks*32 + (lane>>4)*8) ^ ((row&7)<<3))];
            }
            #pragma unroll
            for (int ni = 0; ni < 4; ++ni) {
                int row = wc*64 + ni*16 + (lane & 15);
                bf8[ni] = *(const short8*)&Bs[row*BKG + ((ks*32 + (lane>>4)*8) ^ ((row&7)<<3))];
            }
            #pragma unroll
            for (int mi = 0; mi < 4; ++mi)
                #pragma unroll
                for (int ni = 0; ni < 4; ++ni)
                    acc[mi][ni] = __builtin_amdgcn_mfma_f32_16x16x32_bf16(af[mi], bf8[ni], acc[mi][ni], 0, 0, 0);
        }
    }

    float bv4[4];
    #pragma unroll
    for (int ni = 0; ni < 4; ++ni) bv4[ni] = bias[n0 + wc*64 + ni*16 + (lane & 15)];

    #pragma unroll
    for (int mi = 0; mi < 4; ++mi)
        #pragma unroll
        for (int ni = 0; ni < 4; ++ni) {
            int col = n0 + wc*64 + ni*16 + (lane & 15);
            int rbase = m0 + wr*64 + mi*16 + ((lane>>4)<<2);
            #pragma unroll
            for (int jj = 0; jj < 4; ++jj)
                C[(size_t)(rbase+jj)*D_MODEL + col] = acc[mi][ni][jj] + bv4[ni];
        }
}

// ---------------------------------------------------------------------------
// Flash attention, 32x32 MFMA, KVB=64. K interior rows via global_load_lds
// (pre-swizzled source, linear dest); only the 2 halo rows go through regs.
// (round-19 verified body)
// ---------------------------------------------------------------------------
#define KVB 64
#define NCH (SEQ/KVB)   // 16
#define THR 8.0f

__global__ __launch_bounds__(256, 3) void attn_flash(
    const unsigned short* __restrict__ Qp,
    const unsigned short* __restrict__ Kp,
    const unsigned short* __restrict__ Vt,
    const float* __restrict__ CW,
    unsigned short* __restrict__ Aop)
{
    __shared__ unsigned short Ks[2][66*64];  // rows 0..65 = keys ck*64-1..+64
    __shared__ unsigned short Vs[2][64*64];

    const int tid = threadIdx.x;
    const int lane = tid & 63, wid = tid >> 6;
    const int ql = lane & 31, g = lane >> 5;

    const int bid = blockIdx.x;
    const int sw = (bid & 7) * 96 + (bid >> 3);
    const int q0 = (sw & 7) * 128;
    const int bh = sw >> 3;
    const int h = bh % NH, b = bh / NH;

    float wcv[9];
    #pragma unroll
    for (int i = 0; i < 9; ++i) wcv[i] = CW[h*9 + i];

    const unsigned short* KpB = Kp + (size_t)b*SEQ*D_MODEL + h*DK;
    const unsigned short* QpB = Qp + (size_t)b*SEQ*D_MODEL + h*DK;
    const char* VtB = (const char*)Vt + (size_t)bh*DK*SEQ*2;

    auto kstage = [&](int ck, int buf) {
        #pragma unroll
        for (int u = 0; u < 2; ++u) {
            int p = (tid + u*256) * 16;
            int row = p >> 7, off = p & 127;
            const char* src = (const char*)KpB
                + ((size_t)(ck*KVB + row)*D_MODEL)*2 + (off ^ (((row+1)&7)<<4));
            gload_lds16(src, (char*)Ks[buf] + 128 + p);
        }
    };
    short8 khreg;
    auto khalo_load = [&](int ck) {
        if (tid < 16) {
            int r = (tid >> 3) ? 65 : 0;
            int oct = tid & 7;
            int gk = ck*KVB - 1 + r;
            short8 v = (short8)0;
            if (gk >= 0 && gk < SEQ) v = *(const short8*)&KpB[(size_t)gk*D_MODEL + oct*8];
            khreg = v;
        }
    };
    auto khalo_store = [&](int buf) {
        if (tid < 16) {
            int r = (tid >> 3) ? 65 : 0;
            int oct = tid & 7;
            *(short8*)&Ks[buf][r*64 + ((oct ^ (r&7)) << 3)] = khreg;
        }
    };
    auto vstage = [&](int ck, int buf) {
        #pragma unroll
        for (int u = 0; u < 2; ++u) {
            int p = (tid + u*256) * 16;
            int row = p >> 7, off = p & 127;
            const char* src = VtB + ((size_t)row*SEQ + ck*KVB)*2 + (off ^ ((row&7)<<4));
            gload_lds16(src, (char*)Vs[buf] + p);
        }
    };

    khalo_load(0);

    short8 qtf[3][4];
    {
        int gq = q0 + wid*32 + ql;
        #pragma unroll
        for (int i = 0; i < 4; ++i) {
            int dwin = i*16 + g*8;
            short8 qm = (short8)0, qc, qp8 = (short8)0;
            if (gq > 0)      qm  = *(const short8*)&QpB[(size_t)(gq-1)*D_MODEL + dwin];
            qc = *(const short8*)&QpB[(size_t)gq*D_MODEL + dwin];
            if (gq < SEQ-1)  qp8 = *(const short8*)&QpB[(size_t)(gq+1)*D_MODEL + dwin];
            short8 f0, f1, f2;
            #pragma unroll
            for (int j = 0; j < 8; ++j) {
                float fm = bf2f((unsigned short)qm[j]);
                float fc = bf2f((unsigned short)qc[j]);
                float fp = bf2f((unsigned short)qp8[j]);
                float t0 = (fc - (wcv[1]*fm + wcv[4]*fc + wcv[7]*fp)) * L2E;
                float t1 = -(wcv[0]*fm + wcv[3]*fc + wcv[6]*fp) * L2E;
                float t2 = -(wcv[2]*fm + wcv[5]*fc + wcv[8]*fp) * L2E;
                f0[j] = (short)f2bf(t0);
                f1[j] = (short)f2bf(t1);
                f2[j] = (short)f2bf(t2);
            }
            qtf[0][i] = f0; qtf[1][i] = f1; qtf[2][i] = f2;
        }
    }
    khalo_store(0);
    kstage(0, 0);
    vstage(0, 0);
    __syncthreads();

    float m = -1e30f, l = 0.f;
    f32x16 oac[2];
    oac[0] = (f32x16)(0.f); oac[1] = (f32x16)(0.f);

    int cur = 0;
    for (int ck = 0; ck < NCH; ++ck) {
        if (ck < NCH-1) {
            khalo_load(ck+1);
            kstage(ck+1, cur^1);
            vstage(ck+1, cur^1);
        }

        f32x16 st2[2];
        #pragma unroll
        for (int t = 0; t < 2; ++t) {
            f32x16 s = (f32x16)(0.f);
            #pragma unroll
            for (int sl = 0; sl < 3; ++sl) {
                const int shift = (sl == 0) ? 1 : (sl == 1) ? 0 : 2;
                int ar = t*32 + ql + shift;
                #pragma unroll
                for (int i = 0; i < 4; ++i) {
                    int oct = 2*i + g;
                    short8 a = *(const short8*)&Ks[cur][ar*64 + ((oct ^ (ar&7)) << 3)];
                    s = __builtin_amdgcn_mfma_f32_32x32x16_bf16(a, qtf[sl][i], s, 0, 0, 0);
                }
            }
            st2[t] = s;
        }

        float tmax = -1e30f;
        #pragma unroll
        for (int t = 0; t < 2; ++t)
            #pragma unroll
            for (int j = 0; j < 16; ++j) tmax = fmaxf(tmax, st2[t][j]);
        tmax = fmaxf(tmax, __shfl_xor(tmax, 32));

        if (!__all(tmax - m <= THR)) {
            float mn = fmaxf(m, tmax);
            float r = fast_exp2(m - mn);
            l *= r;
            #pragma unroll
            for (int dt = 0; dt < 2; ++dt)
                #pragma unroll
                for (int j = 0; j < 16; ++j) oac[dt][j] *= r;
            m = mn;
        }
        float lsum = 0.f;
        #pragma unroll
        for (int t = 0; t < 2; ++t)
            #pragma unroll
            for (int j = 0; j < 16; ++j) {
                float e = fast_exp2(st2[t][j] - m);
                st2[t][j] = e;
                lsum += e;
            }
        lsum += __shfl_xor(lsum, 32);
        l += lsum;

        short8 pf[4];
        #pragma unroll
        for (int t = 0; t < 2; ++t) {
            #pragma unroll
            for (int f = 0; f < 2; ++f) {
                const int base = f*8;
                unsigned int x0 = pk_bf16_rn(st2[t][base+0], st2[t][base+1]);
                unsigned int x1 = pk_bf16_rn(st2[t][base+2], st2[t][base+3]);
                unsigned int y0 = pk_bf16_rn(st2[t][base+4], st2[t][base+5]);
                unsigned int y1 = pk_bf16_rn(st2[t][base+6], st2[t][base+7]);
                plswap(x0, y0, g);
                plswap(x1, y1, g);
                u32x4 w = {x0, x1, y0, y1};
                pf[t*2 + f] = __builtin_bit_cast(short8, w);
            }
        }

        #pragma unroll
        for (int f = 0; f < 4; ++f) {
            #pragma unroll
            for (int dt = 0; dt < 2; ++dt) {
                int vr = dt*32 + ql;
                int oct = 2*f + g;
                short8 a = *(const short8*)&Vs[cur][vr*64 + ((oct ^ (vr&7)) << 3)];
                oac[dt] = __builtin_amdgcn_mfma_f32_32x32x16_bf16(a, pf[f], oac[dt], 0, 0, 0);
            }
        }

        if (ck < NCH-1) khalo_store(cur^1);
        __syncthreads();
        cur ^= 1;
    }

    float invl = 1.0f / l;
    int qg = q0 + wid*32 + ql;
    size_t obase = (size_t)(b*SEQ + qg)*D_MODEL + h*DK;
    #pragma unroll
    for (int dt = 0; dt < 2; ++dt) {
        #pragma unroll
        for (int u = 0; u < 4; ++u) {
            int d0 = dt*32 + 8*u + 4*g;
            ushort4v o;
            #pragma unroll
            for (int j = 0; j < 4; ++j) o[j] = f2bf(oac[dt][4*u + j] * invl);
            *(ushort4v*)&Aop[obase + d0] = o;
        }
    }
}

// ---------------------------------------------------------------------------
extern "C" void kernel_launch(void* const* d_in, const int* in_sizes, int n_in,
                              void* d_out, int out_size, void* d_ws, size_t ws_size,
                              hipStream_t stream)
{
    const float* q  = (const float*)d_in[0];
    const float* k  = (const float*)d_in[1];
    const float* v  = (const float*)d_in[2];
    const float* wq = (const float*)d_in[3];
    const float* bq = (const float*)d_in[4];
    const float* wk = (const float*)d_in[5];
    const float* bk = (const float*)d_in[6];
    const float* wv = (const float*)d_in[7];
    const float* bv = (const float*)d_in[8];
    const float* wo = (const float*)d_in[9];
    const float* bo = (const float*)d_in[10];
    const float* cw = (const float*)d_in[11];

    unsigned short* wqb = (unsigned short*)d_ws;
    unsigned short* wkb = wqb + WELT;
    unsigned short* wvb = wkb + WELT;
    unsigned short* wob = wvb + WELT;
    unsigned short* Qp  = wob + WELT;
    unsigned short* Kp  = Qp  + NELT;
    unsigned short* Vtp = Kp  + NELT;
    unsigned short* Aop = Vtp + NELT;

    cvt_w<<<(int)(4*WELT/8/256), 256, 0, stream>>>(wq, wk, wv, wo, wqb, wkb, wvb, wob);

    proj_gemm<<<dim3(1152), 256, 0, stream>>>(q, k, v, wqb, wkb, wvb,
                                              bq, bk, bv, Qp, Kp, Vtp);

    attn_flash<<<dim3(768), 256, 0, stream>>>(Qp, Kp, Vtp, cw, Aop);

    gemm_out<<<dim3(384), 256, 0, stream>>>(Aop, wob, bo, (float*)d_out);
}